// Round 3
// baseline (842.816 us; speedup 1.0000x reference)
//
#include <hip/hip_runtime.h>
#include <hip/hip_bf16.h>
#include <math.h>

#define SEQ 2048
#define DMODEL 1024
#define QH 16
#define KVH 4
#define DH 64
#define TOPK 64
#define KV_D (KVH * DH)   // 256

// ---------------- monotone float<->uint mapping for exact rank selection ----------------
__device__ __forceinline__ unsigned f2u(float f) {
    unsigned u = __float_as_uint(f);
    return (u & 0x80000000u) ? ~u : (u | 0x80000000u);
}
__device__ __forceinline__ float u2f(unsigned u) {
    unsigned v = (u & 0x80000000u) ? (u & 0x7fffffffu) : ~u;
    return __uint_as_float(v);
}

// ---------------- tiled f32 GEMM: C[M,N] = A[M,K] * B[N,K]^T ----------------
__global__ __launch_bounds__(256) void gemm_abT(const float* __restrict__ A,
                                                const float* __restrict__ B,
                                                float* __restrict__ C,
                                                int M, int N, int K) {
    __shared__ float As[16][68];
    __shared__ float Bs[16][68];
    const int tid = threadIdx.x;
    const int m0 = blockIdx.y * 64;
    const int n0 = blockIdx.x * 64;
    const int lr = tid >> 2;          // 0..63
    const int lk = (tid & 3) << 2;    // 0,4,8,12
    const int tx = tid & 15;
    const int ty = tid >> 4;

    float acc[4][4];
#pragma unroll
    for (int a = 0; a < 4; ++a)
#pragma unroll
        for (int b = 0; b < 4; ++b) acc[a][b] = 0.f;

    const float* Ap = A + (size_t)(m0 + lr) * K + lk;
    const float* Bp = B + (size_t)(n0 + lr) * K + lk;

    for (int k0 = 0; k0 < K; k0 += 16) {
        float4 a4 = *(const float4*)(Ap + k0);
        float4 b4 = *(const float4*)(Bp + k0);
        As[lk + 0][lr] = a4.x; As[lk + 1][lr] = a4.y;
        As[lk + 2][lr] = a4.z; As[lk + 3][lr] = a4.w;
        Bs[lk + 0][lr] = b4.x; Bs[lk + 1][lr] = b4.y;
        Bs[lk + 2][lr] = b4.z; Bs[lk + 3][lr] = b4.w;
        __syncthreads();
#pragma unroll
        for (int kk = 0; kk < 16; ++kk) {
            float a0 = As[kk][ty * 4 + 0], a1 = As[kk][ty * 4 + 1];
            float a2 = As[kk][ty * 4 + 2], a3 = As[kk][ty * 4 + 3];
            float b0 = Bs[kk][tx * 4 + 0], b1 = Bs[kk][tx * 4 + 1];
            float b2 = Bs[kk][tx * 4 + 2], b3 = Bs[kk][tx * 4 + 3];
            acc[0][0] += a0 * b0; acc[0][1] += a0 * b1; acc[0][2] += a0 * b2; acc[0][3] += a0 * b3;
            acc[1][0] += a1 * b0; acc[1][1] += a1 * b1; acc[1][2] += a1 * b2; acc[1][3] += a1 * b3;
            acc[2][0] += a2 * b0; acc[2][1] += a2 * b1; acc[2][2] += a2 * b2; acc[2][3] += a2 * b3;
            acc[3][0] += a3 * b0; acc[3][1] += a3 * b1; acc[3][2] += a3 * b2; acc[3][3] += a3 * b3;
        }
        __syncthreads();
    }
#pragma unroll
    for (int ii = 0; ii < 4; ++ii)
#pragma unroll
        for (int jj = 0; jj < 4; ++jj)
            C[(size_t)(m0 + ty * 4 + ii) * N + n0 + tx * 4 + jj] = acc[ii][jj];
}

// ---------------- RoPE on q, in place ----------------
__global__ __launch_bounds__(256) void rope_q_kernel(float* __restrict__ q) {
    int idx = blockIdx.x * 256 + threadIdx.x;
    if (idx >= SEQ * QH * 32) return;
    int t = idx >> 9;
    int rem = idx & 511;
    int head = rem >> 5;
    int d = rem & 31;
    float inv = powf(10000.0f, -(float)d * (1.0f / 32.0f));
    float ang = (float)t * inv;
    float s, c;
    sincosf(ang, &s, &c);
    float* p = q + (size_t)t * DMODEL + head * DH + d;
    float lo = p[0], hi = p[32];
    p[0] = lo * c - hi * s;
    p[32] = hi * c + lo * s;
}

// ---------------- RoPE on k + transpose to kT[(head*64+d)][t] ----------------
__global__ __launch_bounds__(256) void rope_k_t_kernel(const float* __restrict__ ktmp,
                                                       float* __restrict__ kT) {
    int idx = blockIdx.x * 256 + threadIdx.x;
    if (idx >= SEQ * KVH * 32) return;
    int t = idx >> 7;
    int rem = idx & 127;
    int head = rem >> 5;
    int d = rem & 31;
    float inv = powf(10000.0f, -(float)d * (1.0f / 32.0f));
    float ang = (float)t * inv;
    float s, c;
    sincosf(ang, &s, &c);
    const float* p = ktmp + (size_t)t * KV_D + head * DH + d;
    float lo = p[0], hi = p[32];
    kT[(size_t)(head * DH + d) * SEQ + t] = lo * c - hi * s;
    kT[(size_t)(head * DH + d + 32) * SEQ + t] = hi * c + lo * s;
}

// ---------------- AV helper: process one 64-lane group of weights ----------------
__device__ __forceinline__ void av_group(float w, int jbase, const float* __restrict__ vb,
                                         float& acc) {
    unsigned long long mk = __ballot(w > 0.f);
    while (mk) {
        int l = __ffsll((unsigned long long)mk) - 1;
        mk &= mk - 1;
        float wj = __shfl(w, l, 64);
        acc += wj * vb[(size_t)(jbase + l * 4) * KV_D];
    }
}

// ---------------- attention: one WAVE per 4 query rows of one head ----------------
// wave g: h = g&15, grp = g>>4, rows i0..i0+3 with i0=(511-grp)*4 (longest first).
// The 4 waves of a block share grp and kvh -> identical K reads served by L1.
__global__ __launch_bounds__(256, 2) void attn_wave4(const float* __restrict__ q,
                                                     const float* __restrict__ kT,
                                                     const float* __restrict__ v,
                                                     float* __restrict__ out) {
    const int lane = threadIdx.x & 63;
    const int g = blockIdx.x * 4 + (threadIdx.x >> 6);   // 0..8191
    const int h = g & 15;
    const int grp = g >> 4;                              // 0..511
    const int i0 = (511 - grp) * 4;
    const int imax = i0 + 3;
    const int kvh = h >> 2;

    const float* kbase = kT + (size_t)(kvh * DH) * SEQ;
    const float* qp0 = q + (size_t)i0 * DMODEL + h * DH; // wave-uniform

    // ordered-uint scores: uv[query][chunk]; slot (c,lane,e) -> j = c*256 + lane*4 + e
    uint4 uv[4][8];
#pragma unroll
    for (int qq = 0; qq < 4; ++qq)
#pragma unroll
        for (int c = 0; c < 8; ++c) uv[qq][c] = make_uint4(0u, 0u, 0u, 0u);

#pragma unroll
    for (int c = 0; c < 8; ++c) {
        if (c * 256 <= imax) {                           // wave-uniform
            const int j0 = c * 256 + lane * 4;
            const float* kp = kbase + j0;
            float4 a[4];
#pragma unroll
            for (int qq = 0; qq < 4; ++qq) a[qq] = make_float4(0.f, 0.f, 0.f, 0.f);
#pragma unroll 8
            for (int d = 0; d < 64; ++d) {
                float4 k4 = *(const float4*)kp;
                kp += SEQ;
#pragma unroll
                for (int qq = 0; qq < 4; ++qq) {
                    float qd = qp0[qq * DMODEL + d];     // uniform -> s_load
                    a[qq].x += qd * k4.x; a[qq].y += qd * k4.y;
                    a[qq].z += qd * k4.z; a[qq].w += qd * k4.w;
                }
            }
#pragma unroll
            for (int qq = 0; qq < 4; ++qq) {
                const int iq = i0 + qq;
                uv[qq][c].x = (j0 + 0 <= iq) ? f2u(a[qq].x * 0.125f) : 0u;
                uv[qq][c].y = (j0 + 1 <= iq) ? f2u(a[qq].y * 0.125f) : 0u;
                uv[qq][c].z = (j0 + 2 <= iq) ? f2u(a[qq].z * 0.125f) : 0u;
                uv[qq][c].w = (j0 + 3 <= iq) ? f2u(a[qq].w * 0.125f) : 0u;
            }
        }
    }

    const float* vb = v + kvh * DH + lane;               // v layout [j][KV_D]

#pragma unroll
    for (int qq = 0; qq < 4; ++qq) {
        const int iq = i0 + qq;

        // ---- row max (ordered-uint domain; invalid slots are 0) ----
        unsigned um = 0u;
#pragma unroll
        for (int c = 0; c < 8; ++c) {
            um = max(um, max(max(uv[qq][c].x, uv[qq][c].y), max(uv[qq][c].z, uv[qq][c].w)));
        }
#pragma unroll
        for (int o = 32; o > 0; o >>= 1) um = max(um, (unsigned)__shfl_xor((int)um, o, 64));
        const float m = u2f(um);

        // ---- exact 64th-largest: max p with count(u >= p) >= 64 (ballot counting) ----
        unsigned p = 1u;                                  // iq < 64: keep every valid entry
        if (iq >= TOPK) {
            p = 0u;
            for (int b = 31; b >= 0; --b) {
                unsigned cand = p | (1u << b);
                int cnt = 0;
#pragma unroll
                for (int c = 0; c < 8; ++c) {
                    cnt += __popcll(__ballot(uv[qq][c].x >= cand));
                    cnt += __popcll(__ballot(uv[qq][c].y >= cand));
                    cnt += __popcll(__ballot(uv[qq][c].z >= cand));
                    cnt += __popcll(__ballot(uv[qq][c].w >= cand));
                }
                if (cnt >= TOPK) p = cand;                // cnt uniform (ballot)
            }
        }

        // ---- weights (keep u >= p, exact tie semantics) ----
        float4 w[8];
        float lsum = 0.f;
#pragma unroll
        for (int c = 0; c < 8; ++c) {
            w[c].x = (uv[qq][c].x >= p) ? __expf(u2f(uv[qq][c].x) - m) : 0.f;
            w[c].y = (uv[qq][c].y >= p) ? __expf(u2f(uv[qq][c].y) - m) : 0.f;
            w[c].z = (uv[qq][c].z >= p) ? __expf(u2f(uv[qq][c].z) - m) : 0.f;
            w[c].w = (uv[qq][c].w >= p) ? __expf(u2f(uv[qq][c].w) - m) : 0.f;
            lsum += (w[c].x + w[c].y) + (w[c].z + w[c].w);
        }
        float den = lsum;
#pragma unroll
        for (int o = 32; o > 0; o >>= 1) den += __shfl_xor(den, o, 64);

        // ---- AV: ballot kept weights, broadcast, accumulate; lane = output dim ----
        float acc = 0.f;
#pragma unroll
        for (int c = 0; c < 8; ++c) {
            if (c * 256 <= iq) {                          // wave-uniform
                av_group(w[c].x, c * 256 + 0, vb, acc);
                av_group(w[c].y, c * 256 + 1, vb, acc);
                av_group(w[c].z, c * 256 + 2, vb, acc);
                av_group(w[c].w, c * 256 + 3, vb, acc);
            }
        }

        out[(size_t)iq * DMODEL + h * DH + lane] = acc / den;
    }
}

extern "C" void kernel_launch(void* const* d_in, const int* in_sizes, int n_in,
                              void* d_out, int out_size, void* d_ws, size_t ws_size,
                              hipStream_t stream) {
    const float* x  = (const float*)d_in[0];
    const float* Wq = (const float*)d_in[1];
    const float* Wk = (const float*)d_in[2];
    const float* Wv = (const float*)d_in[3];
    const float* Wo = (const float*)d_in[4];
    float* out = (float*)d_out;

    float* ws = (float*)d_ws;
    float* q    = ws;                               // 2048*1024
    float* kT   = q + (size_t)SEQ * DMODEL;         // 256*2048
    float* vv   = kT + (size_t)KV_D * SEQ;          // 2048*256
    float* attn = vv + (size_t)SEQ * KV_D;          // 2048*1024
    float* ktmp = attn + (size_t)SEQ * DMODEL;      // 2048*256

    dim3 blk(256);

    // QKV projections
    gemm_abT<<<dim3(DMODEL / 64, SEQ / 64), blk, 0, stream>>>(x, Wq, q, SEQ, DMODEL, DMODEL);
    gemm_abT<<<dim3(KV_D / 64, SEQ / 64), blk, 0, stream>>>(x, Wk, ktmp, SEQ, KV_D, DMODEL);
    gemm_abT<<<dim3(KV_D / 64, SEQ / 64), blk, 0, stream>>>(x, Wv, vv, SEQ, KV_D, DMODEL);

    // RoPE
    rope_q_kernel<<<(SEQ * QH * 32 + 255) / 256, blk, 0, stream>>>(q);
    rope_k_t_kernel<<<(SEQ * KVH * 32 + 255) / 256, blk, 0, stream>>>(ktmp, kT);

    // attention: one wave per 4 rows, L1-aligned K sharing across the block
    attn_wave4<<<(SEQ * QH) / 16, blk, 0, stream>>>(q, kT, vv, attn);

    // output projection
    gemm_abT<<<dim3(DMODEL / 64, SEQ / 64), blk, 0, stream>>>(attn, Wo, out, SEQ, DMODEL, DMODEL);
}

// Round 4
// 719.489 us; speedup vs baseline: 1.1714x; 1.1714x over previous
//
#include <hip/hip_runtime.h>
#include <hip/hip_bf16.h>
#include <math.h>

#define SEQ 2048
#define DMODEL 1024
#define QH 16
#define KVH 4
#define DH 64
#define TOPK 64
#define KV_D (KVH * DH)   // 256

// ---------------- monotone float<->uint mapping for exact rank selection ----------------
__device__ __forceinline__ unsigned f2u(float f) {
    unsigned u = __float_as_uint(f);
    return (u & 0x80000000u) ? ~u : (u | 0x80000000u);
}
__device__ __forceinline__ float u2f(unsigned u) {
    unsigned v = (u & 0x80000000u) ? (u & 0x7fffffffu) : ~u;
    return __uint_as_float(v);
}

// ---------------- tiled f32 GEMM: C[M,N] = A[M,K] * B[N,K]^T ----------------
__global__ __launch_bounds__(256) void gemm_abT(const float* __restrict__ A,
                                                const float* __restrict__ B,
                                                float* __restrict__ C,
                                                int M, int N, int K) {
    __shared__ float As[16][68];
    __shared__ float Bs[16][68];
    const int tid = threadIdx.x;
    const int m0 = blockIdx.y * 64;
    const int n0 = blockIdx.x * 64;
    const int lr = tid >> 2;          // 0..63
    const int lk = (tid & 3) << 2;    // 0,4,8,12
    const int tx = tid & 15;
    const int ty = tid >> 4;

    float acc[4][4];
#pragma unroll
    for (int a = 0; a < 4; ++a)
#pragma unroll
        for (int b = 0; b < 4; ++b) acc[a][b] = 0.f;

    const float* Ap = A + (size_t)(m0 + lr) * K + lk;
    const float* Bp = B + (size_t)(n0 + lr) * K + lk;

    for (int k0 = 0; k0 < K; k0 += 16) {
        float4 a4 = *(const float4*)(Ap + k0);
        float4 b4 = *(const float4*)(Bp + k0);
        As[lk + 0][lr] = a4.x; As[lk + 1][lr] = a4.y;
        As[lk + 2][lr] = a4.z; As[lk + 3][lr] = a4.w;
        Bs[lk + 0][lr] = b4.x; Bs[lk + 1][lr] = b4.y;
        Bs[lk + 2][lr] = b4.z; Bs[lk + 3][lr] = b4.w;
        __syncthreads();
#pragma unroll
        for (int kk = 0; kk < 16; ++kk) {
            float a0 = As[kk][ty * 4 + 0], a1 = As[kk][ty * 4 + 1];
            float a2 = As[kk][ty * 4 + 2], a3 = As[kk][ty * 4 + 3];
            float b0 = Bs[kk][tx * 4 + 0], b1 = Bs[kk][tx * 4 + 1];
            float b2 = Bs[kk][tx * 4 + 2], b3 = Bs[kk][tx * 4 + 3];
            acc[0][0] += a0 * b0; acc[0][1] += a0 * b1; acc[0][2] += a0 * b2; acc[0][3] += a0 * b3;
            acc[1][0] += a1 * b0; acc[1][1] += a1 * b1; acc[1][2] += a1 * b2; acc[1][3] += a1 * b3;
            acc[2][0] += a2 * b0; acc[2][1] += a2 * b1; acc[2][2] += a2 * b2; acc[2][3] += a2 * b3;
            acc[3][0] += a3 * b0; acc[3][1] += a3 * b1; acc[3][2] += a3 * b2; acc[3][3] += a3 * b3;
        }
        __syncthreads();
    }
#pragma unroll
    for (int ii = 0; ii < 4; ++ii)
#pragma unroll
        for (int jj = 0; jj < 4; ++jj)
            C[(size_t)(m0 + ty * 4 + ii) * N + n0 + tx * 4 + jj] = acc[ii][jj];
}

// ---------------- RoPE on q, in place ----------------
__global__ __launch_bounds__(256) void rope_q_kernel(float* __restrict__ q) {
    int idx = blockIdx.x * 256 + threadIdx.x;
    if (idx >= SEQ * QH * 32) return;
    int t = idx >> 9;
    int rem = idx & 511;
    int head = rem >> 5;
    int d = rem & 31;
    float inv = powf(10000.0f, -(float)d * (1.0f / 32.0f));
    float ang = (float)t * inv;
    float s, c;
    sincosf(ang, &s, &c);
    float* p = q + (size_t)t * DMODEL + head * DH + d;
    float lo = p[0], hi = p[32];
    p[0] = lo * c - hi * s;
    p[32] = hi * c + lo * s;
}

// ---------------- RoPE on k + transpose to kT[(head*64+d)][t] ----------------
__global__ __launch_bounds__(256) void rope_k_t_kernel(const float* __restrict__ ktmp,
                                                       float* __restrict__ kT) {
    int idx = blockIdx.x * 256 + threadIdx.x;
    if (idx >= SEQ * KVH * 32) return;
    int t = idx >> 7;
    int rem = idx & 127;
    int head = rem >> 5;
    int d = rem & 31;
    float inv = powf(10000.0f, -(float)d * (1.0f / 32.0f));
    float ang = (float)t * inv;
    float s, c;
    sincosf(ang, &s, &c);
    const float* p = ktmp + (size_t)t * KV_D + head * DH + d;
    float lo = p[0], hi = p[32];
    kT[(size_t)(head * DH + d) * SEQ + t] = lo * c - hi * s;
    kT[(size_t)(head * DH + d + 32) * SEQ + t] = hi * c + lo * s;
}

// ---------------- AV helper: process one 64-lane group of weights ----------------
__device__ __forceinline__ void av_group(float w, int jbase, const float* __restrict__ vb,
                                         float& acc) {
    unsigned long long mk = __ballot(w > 0.f);
    while (mk) {
        int l = __ffsll((unsigned long long)mk) - 1;
        mk &= mk - 1;
        float wj = __shfl(w, l, 64);
        acc += wj * vb[(size_t)(jbase + l * 4) * KV_D];
    }
}

// ---------------- attention: one WAVE per (query i, head h); no LDS, no syncthreads ----------------
// 4 waves of a block = consecutive i, same head -> identical K streams served by L1.
__global__ __launch_bounds__(256, 3) void attn_wave(const float* __restrict__ q,
                                                    const float* __restrict__ kT,
                                                    const float* __restrict__ v,
                                                    float* __restrict__ out) {
    const int lane = threadIdx.x & 63;
    const int r = blockIdx.x * 4 + (threadIdx.x >> 6);
    const int h = r >> 11;
    const int i = r & (SEQ - 1);
    const int kvh = h >> 2;

    const float* qp = q + (size_t)i * DMODEL + h * DH;   // wave-uniform address
    const float* kbase = kT + (size_t)(kvh * DH) * SEQ;

    // ---- scores: lane owns j = c*256 + lane*4 + {0..3} ----
    float4 sc[8];
#pragma unroll
    for (int c = 0; c < 8; ++c) {
        sc[c] = make_float4(-INFINITY, -INFINITY, -INFINITY, -INFINITY);
        if (c * 256 <= i) {                       // wave-uniform branch
            const int j0 = c * 256 + lane * 4;
            const float* kp = kbase + j0;
            float ax = 0.f, ay = 0.f, az = 0.f, aw = 0.f;
#pragma unroll 8
            for (int d = 0; d < 64; ++d) {
                float qd = qp[d];                 // uniform -> s_load
                float4 k4 = *(const float4*)kp;
                kp += SEQ;
                ax += qd * k4.x; ay += qd * k4.y;
                az += qd * k4.z; aw += qd * k4.w;
            }
            sc[c].x = (j0 + 0 <= i) ? ax * 0.125f : -INFINITY;
            sc[c].y = (j0 + 1 <= i) ? ay * 0.125f : -INFINITY;
            sc[c].z = (j0 + 2 <= i) ? az * 0.125f : -INFINITY;
            sc[c].w = (j0 + 3 <= i) ? aw * 0.125f : -INFINITY;
        }
    }

    // ---- row max (valid entries; invalid are -inf) ----
    float m = -INFINITY;
#pragma unroll
    for (int c = 0; c < 8; ++c)
        m = fmaxf(m, fmaxf(fmaxf(sc[c].x, sc[c].y), fmaxf(sc[c].z, sc[c].w)));
#pragma unroll
    for (int o = 32; o > 0; o >>= 1) m = fmaxf(m, __shfl_xor(m, o, 64));

    // ---- ordered-uint view; invalid entries -> 0 (below any finite score) ----
    uint4 uv[8];
#pragma unroll
    for (int c = 0; c < 8; ++c) {
        uv[c].x = (sc[c].x == -INFINITY) ? 0u : f2u(sc[c].x);
        uv[c].y = (sc[c].y == -INFINITY) ? 0u : f2u(sc[c].y);
        uv[c].z = (sc[c].z == -INFINITY) ? 0u : f2u(sc[c].z);
        uv[c].w = (sc[c].w == -INFINITY) ? 0u : f2u(sc[c].w);
    }

    // ---- exact 64th-largest: max p with count(u >= p) >= 64 ----
    // ballot counting: v_cmp -> sgpr pair, s_bcnt1 on scalar pipe; no shuffles.
    unsigned p = 1u;                 // i+1 <= 64: keep every valid entry (valid u >= 1)
    if (i >= TOPK) {
        p = 0u;
        for (int b = 31; b >= 0; --b) {
            unsigned cand = p | (1u << b);
            int cnt = 0;
#pragma unroll
            for (int c = 0; c < 8; ++c) {
                cnt += __popcll(__ballot(uv[c].x >= cand));
                cnt += __popcll(__ballot(uv[c].y >= cand));
                cnt += __popcll(__ballot(uv[c].z >= cand));
                cnt += __popcll(__ballot(uv[c].w >= cand));
            }
            if (cnt >= TOPK) p = cand;           // cnt uniform (ballot-derived)
        }
    }

    // ---- weights: keep u >= p (exact tie semantics), softmax numerators ----
    float lsum = 0.f;
#pragma unroll
    for (int c = 0; c < 8; ++c) {
        float wx = (uv[c].x >= p) ? __expf(sc[c].x - m) : 0.f;
        float wy = (uv[c].y >= p) ? __expf(sc[c].y - m) : 0.f;
        float wz = (uv[c].z >= p) ? __expf(sc[c].z - m) : 0.f;
        float ww = (uv[c].w >= p) ? __expf(sc[c].w - m) : 0.f;
        sc[c].x = wx; sc[c].y = wy; sc[c].z = wz; sc[c].w = ww;
        lsum += (wx + wy) + (wz + ww);
    }
    float den = lsum;
#pragma unroll
    for (int o = 32; o > 0; o >>= 1) den += __shfl_xor(den, o, 64);

    // ---- AV: ballot kept weights, broadcast, accumulate; lane = output dim ----
    float acc = 0.f;
    const float* vb = v + kvh * DH + lane;       // v layout [j][KV_D]
#pragma unroll
    for (int c = 0; c < 8; ++c) {
        if (c * 256 <= i) {                      // wave-uniform
            av_group(sc[c].x, c * 256 + 0, vb, acc);
            av_group(sc[c].y, c * 256 + 1, vb, acc);
            av_group(sc[c].z, c * 256 + 2, vb, acc);
            av_group(sc[c].w, c * 256 + 3, vb, acc);
        }
    }

    out[(size_t)i * DMODEL + h * DH + lane] = acc / den;
}

extern "C" void kernel_launch(void* const* d_in, const int* in_sizes, int n_in,
                              void* d_out, int out_size, void* d_ws, size_t ws_size,
                              hipStream_t stream) {
    const float* x  = (const float*)d_in[0];
    const float* Wq = (const float*)d_in[1];
    const float* Wk = (const float*)d_in[2];
    const float* Wv = (const float*)d_in[3];
    const float* Wo = (const float*)d_in[4];
    float* out = (float*)d_out;

    float* ws = (float*)d_ws;
    float* q    = ws;                               // 2048*1024
    float* kT   = q + (size_t)SEQ * DMODEL;         // 256*2048
    float* vv   = kT + (size_t)KV_D * SEQ;          // 2048*256
    float* attn = vv + (size_t)SEQ * KV_D;          // 2048*1024
    float* ktmp = attn + (size_t)SEQ * DMODEL;      // 2048*256

    dim3 blk(256);

    // QKV projections
    gemm_abT<<<dim3(DMODEL / 64, SEQ / 64), blk, 0, stream>>>(x, Wq, q, SEQ, DMODEL, DMODEL);
    gemm_abT<<<dim3(KV_D / 64, SEQ / 64), blk, 0, stream>>>(x, Wk, ktmp, SEQ, KV_D, DMODEL);
    gemm_abT<<<dim3(KV_D / 64, SEQ / 64), blk, 0, stream>>>(x, Wv, vv, SEQ, KV_D, DMODEL);

    // RoPE
    rope_q_kernel<<<(SEQ * QH * 32 + 255) / 256, blk, 0, stream>>>(q);
    rope_k_t_kernel<<<(SEQ * KVH * 32 + 255) / 256, blk, 0, stream>>>(ktmp, kT);

    // attention: one wave per (i, h) row
    attn_wave<<<(SEQ * QH) / 4, blk, 0, stream>>>(q, kT, vv, attn);

    // output projection
    gemm_abT<<<dim3(DMODEL / 64, SEQ / 64), blk, 0, stream>>>(attn, Wo, out, SEQ, DMODEL, DMODEL);
}

// Round 5
// 566.063 us; speedup vs baseline: 1.4889x; 1.2710x over previous
//
#include <hip/hip_runtime.h>
#include <hip/hip_bf16.h>
#include <math.h>

#define SEQ 2048
#define DMODEL 1024
#define QH 16
#define KVH 4
#define DH 64
#define TOPK 64
#define KV_D (KVH * DH)   // 256
#define CAP 128

typedef __attribute__((ext_vector_type(8))) short short8;
typedef __attribute__((ext_vector_type(4))) float floatx4;

// ---------------- monotone float<->uint mapping for exact rank selection ----------------
__device__ __forceinline__ unsigned f2u(float f) {
    unsigned u = __float_as_uint(f);
    return (u & 0x80000000u) ? ~u : (u | 0x80000000u);
}
__device__ __forceinline__ float u2f(unsigned u) {
    unsigned v = (u & 0x80000000u) ? (u & 0x7fffffffu) : ~u;
    return __uint_as_float(v);
}
__device__ __forceinline__ unsigned short f2bf(float x) {   // RNE f32->bf16
    unsigned u = __float_as_uint(x);
    return (unsigned short)((u + 0x7fffu + ((u >> 16) & 1u)) >> 16);
}

// ---------------- f32 -> bf16 convert (vectorized x4) ----------------
__global__ __launch_bounds__(256) void cvt_bf16(const float* __restrict__ in,
                                                unsigned short* __restrict__ out, int n4) {
    int idx = blockIdx.x * 256 + threadIdx.x;
    if (idx >= n4) return;
    float4 f = ((const float4*)in)[idx];
    ushort4 o;
    o.x = f2bf(f.x); o.y = f2bf(f.y); o.z = f2bf(f.z); o.w = f2bf(f.w);
    ((ushort4*)out)[idx] = o;
}

// ---------------- async 16B global->LDS ----------------
__device__ __forceinline__ void async16(const void* g, void* l) {
    __builtin_amdgcn_global_load_lds(
        (const __attribute__((address_space(1))) unsigned int*)g,
        (__attribute__((address_space(3))) unsigned int*)l, 16, 0, 0);
}

// ---------------- MFMA bf16 GEMM: C[M,N] f32 = A[M,K]bf16 * B[N,K]bf16 ^T ----------------
// tile 128x128, BK=32, 4 waves (2x2 quadrants of 64x64), XOR-swizzled LDS.
__global__ __launch_bounds__(256, 2) void gemm_mfma(const unsigned short* __restrict__ A,
                                                    const unsigned short* __restrict__ B,
                                                    float* __restrict__ C,
                                                    int M, int N, int K) {
    __shared__ unsigned short ldsA[128 * 32];
    __shared__ unsigned short ldsB[128 * 32];
    const int tid = threadIdx.x;
    const int lane = tid & 63;
    const int wid = tid >> 6;
    const int m0 = blockIdx.y * 128, n0 = blockIdx.x * 128;
    const int mq = (wid >> 1) * 64, nq = (wid & 1) * 64;

    floatx4 acc[4][4];
#pragma unroll
    for (int a = 0; a < 4; ++a)
#pragma unroll
        for (int b = 0; b < 4; ++b) acc[a][b] = (floatx4){0.f, 0.f, 0.f, 0.f};

    // staging: thread t covers rows (t>>2) and (t>>2)+64, swizzled k-block
    const int srow = tid >> 2;
    const int skb = (tid & 3) ^ ((tid >> 3) & 3);
    const unsigned short* Ag = A + (size_t)(m0 + srow) * K + skb * 8;
    const unsigned short* Bg = B + (size_t)(n0 + srow) * K + skb * 8;
    unsigned lbase = __builtin_amdgcn_readfirstlane((unsigned)(wid * 1024));
    char* la = (char*)ldsA + lbase;
    char* lb = (char*)ldsB + lbase;

    for (int k0 = 0; k0 < K; k0 += 32) {
        async16(Ag + k0, la);
        async16(Ag + (size_t)64 * K + k0, la + 4096);
        async16(Bg + k0, lb);
        async16(Bg + (size_t)64 * K + k0, lb + 4096);
        __syncthreads();   // drains vmcnt, LDS tiles visible

        short8 af[4], bf[4];
#pragma unroll
        for (int mt = 0; mt < 4; ++mt) {
            int row = mq + mt * 16 + (lane & 15);
            int s = ((lane >> 4) ^ ((row >> 1) & 3)) * 8;
            af[mt] = *(const short8*)&ldsA[row * 32 + s];
        }
#pragma unroll
        for (int nt = 0; nt < 4; ++nt) {
            int row = nq + nt * 16 + (lane & 15);
            int s = ((lane >> 4) ^ ((row >> 1) & 3)) * 8;
            bf[nt] = *(const short8*)&ldsB[row * 32 + s];
        }
#pragma unroll
        for (int mt = 0; mt < 4; ++mt)
#pragma unroll
            for (int nt = 0; nt < 4; ++nt)
                acc[mt][nt] = __builtin_amdgcn_mfma_f32_16x16x32_bf16(af[mt], bf[nt], acc[mt][nt], 0, 0, 0);
        __syncthreads();
    }

    // epilogue: C/D layout col=lane&15, row=(lane>>4)*4+reg
#pragma unroll
    for (int mt = 0; mt < 4; ++mt) {
#pragma unroll
        for (int nt = 0; nt < 4; ++nt) {
            int col = n0 + nq + nt * 16 + (lane & 15);
            int rbase = m0 + mq + mt * 16 + (lane >> 4) * 4;
#pragma unroll
            for (int rr = 0; rr < 4; ++rr)
                C[(size_t)(rbase + rr) * N + col] = acc[mt][nt][rr];
        }
    }
}

// ---------------- RoPE on q, in place ----------------
__global__ __launch_bounds__(256) void rope_q_kernel(float* __restrict__ q) {
    int idx = blockIdx.x * 256 + threadIdx.x;
    if (idx >= SEQ * QH * 32) return;
    int t = idx >> 9;
    int rem = idx & 511;
    int head = rem >> 5;
    int d = rem & 31;
    float inv = powf(10000.0f, -(float)d * (1.0f / 32.0f));
    float ang = (float)t * inv;
    float s, c;
    sincosf(ang, &s, &c);
    float* p = q + (size_t)t * DMODEL + head * DH + d;
    float lo = p[0], hi = p[32];
    p[0] = lo * c - hi * s;
    p[32] = hi * c + lo * s;
}

// ---------------- RoPE on k + transpose to kT[(head*64+d)][t] ----------------
__global__ __launch_bounds__(256) void rope_k_t_kernel(const float* __restrict__ ktmp,
                                                       float* __restrict__ kT) {
    int idx = blockIdx.x * 256 + threadIdx.x;
    if (idx >= SEQ * KVH * 32) return;
    int t = idx >> 7;
    int rem = idx & 127;
    int head = rem >> 5;
    int d = rem & 31;
    float inv = powf(10000.0f, -(float)d * (1.0f / 32.0f));
    float ang = (float)t * inv;
    float s, c;
    sincosf(ang, &s, &c);
    const float* p = ktmp + (size_t)t * KV_D + head * DH + d;
    float lo = p[0], hi = p[32];
    kT[(size_t)(head * DH + d) * SEQ + t] = lo * c - hi * s;
    kT[(size_t)(head * DH + d + 32) * SEQ + t] = hi * c + lo * s;
}

// ---------------- AV fallback helper (arbitrary kept count, exact) ----------------
__device__ __forceinline__ void av_group(float w, int jbase, const float* __restrict__ vb,
                                         float& acc) {
    unsigned long long mk = __ballot(w > 0.f);
    while (mk) {
        int l = __ffsll((unsigned long long)mk) - 1;
        mk &= mk - 1;
        float wj = __shfl(w, l, 64);
        acc += wj * vb[(size_t)(jbase + l * 4) * KV_D];
    }
}

// ---------------- attention: one WAVE per (query i, head h) ----------------
__global__ __launch_bounds__(256, 6) void attn_wave(const float* __restrict__ q,
                                                    const float* __restrict__ kT,
                                                    const float* __restrict__ v,
                                                    unsigned short* __restrict__ outb) {
    const int lane = threadIdx.x & 63;
    const int wid = threadIdx.x >> 6;
    const int r = blockIdx.x * 4 + wid;
    const int h = r >> 11;
    const int i = r & (SEQ - 1);
    const int kvh = h >> 2;

    __shared__ float s_w[4][CAP];
    __shared__ int s_j[4][CAP];

    const float* kbase = kT + (size_t)(kvh * DH) * SEQ;

    // scalarized q-row pointer -> s_load on scalar pipe
    const float* qp = q + (size_t)i * DMODEL + h * DH;
    uintptr_t qa = (uintptr_t)qp;
    unsigned qlo = __builtin_amdgcn_readfirstlane((unsigned)qa);
    unsigned qhi = __builtin_amdgcn_readfirstlane((unsigned)(qa >> 32));
    const float* qs = (const float*)((((uintptr_t)qhi) << 32) | (uintptr_t)qlo);

    // ---- scores in ordered-uint form; slot (c,lane,e) -> j = c*256 + lane*4 + e ----
    uint4 uv[8];
#pragma unroll
    for (int c = 0; c < 8; ++c) {
        uv[c] = make_uint4(0u, 0u, 0u, 0u);
        if (c * 256 <= i) {                       // wave-uniform
            const int j0 = c * 256 + lane * 4;
            const float* kp = kbase + j0;
            float ax = 0.f, ay = 0.f, az = 0.f, aw = 0.f;
#pragma unroll 8
            for (int d = 0; d < 64; ++d) {
                float qd = qs[d];                 // scalar load
                float4 k4 = *(const float4*)kp;
                kp += SEQ;
                ax += qd * k4.x; ay += qd * k4.y;
                az += qd * k4.z; aw += qd * k4.w;
            }
            uv[c].x = (j0 + 0 <= i) ? f2u(ax * 0.125f) : 0u;
            uv[c].y = (j0 + 1 <= i) ? f2u(ay * 0.125f) : 0u;
            uv[c].z = (j0 + 2 <= i) ? f2u(az * 0.125f) : 0u;
            uv[c].w = (j0 + 3 <= i) ? f2u(aw * 0.125f) : 0u;
        }
    }

    // ---- row max in uint domain ----
    unsigned um = 0u;
#pragma unroll
    for (int c = 0; c < 8; ++c)
        um = max(um, max(max(uv[c].x, uv[c].y), max(uv[c].z, uv[c].w)));
#pragma unroll
    for (int o = 32; o > 0; o >>= 1) um = max(um, (unsigned)__shfl_xor((int)um, o, 64));
    const float mf = u2f(um);

    // ---- exact 64th-largest: max p with count(u >= p) >= 64 (ballot counting) ----
    unsigned p = 1u;
    if (i >= TOPK) {
        p = 0u;
        for (int b = 31; b >= 0; --b) {
            unsigned cand = p | (1u << b);
            int cnt = 0;
#pragma unroll
            for (int c = 0; c < 8; ++c) {
                cnt += __popcll(__ballot(uv[c].x >= cand));
                cnt += __popcll(__ballot(uv[c].y >= cand));
                cnt += __popcll(__ballot(uv[c].z >= cand));
                cnt += __popcll(__ballot(uv[c].w >= cand));
            }
            if (cnt >= TOPK) p = cand;
        }
    }

    // ---- compact kept (j, w) into per-wave LDS via ballot prefix ----
    const unsigned long long lmask = (lane == 0) ? 0ull : (~0ull >> (64 - lane));
    int base = 0;
#pragma unroll
    for (int c = 0; c < 8; ++c) {
#pragma unroll
        for (int e = 0; e < 4; ++e) {
            unsigned u = (e == 0) ? uv[c].x : (e == 1) ? uv[c].y : (e == 2) ? uv[c].z : uv[c].w;
            bool keep = (u >= p);
            unsigned long long mk = __ballot(keep);
            if (keep) {
                int pos = base + __popcll(mk & lmask);
                if (pos < CAP) {
                    s_j[wid][pos] = c * 256 + lane * 4 + e;
                    s_w[wid][pos] = __expf(u2f(u) - mf);
                }
            }
            base += (int)__popcll(mk);
        }
    }

    const float* vb = v + kvh * DH + lane;       // v layout [j][KV_D]
    float acc = 0.f, den = 0.f;

    if (base <= CAP) {
        // ---- fast AV: fixed-trip pipelined gather ----
#pragma unroll 8
        for (int l = 0; l < base; ++l) {
            float w = s_w[wid][l];               // broadcast ds_read
            int j = s_j[wid][l];
            acc += w * vb[(size_t)j * KV_D];
            den += w;
        }
    } else {
        // ---- fallback (massive ties): exact slow path ----
        float lsum = 0.f;
#pragma unroll
        for (int c = 0; c < 8; ++c) {
            if (c * 256 <= i) {
                float w0 = (uv[c].x >= p) ? __expf(u2f(uv[c].x) - mf) : 0.f;
                float w1 = (uv[c].y >= p) ? __expf(u2f(uv[c].y) - mf) : 0.f;
                float w2 = (uv[c].z >= p) ? __expf(u2f(uv[c].z) - mf) : 0.f;
                float w3 = (uv[c].w >= p) ? __expf(u2f(uv[c].w) - mf) : 0.f;
                lsum += (w0 + w1) + (w2 + w3);
                av_group(w0, c * 256 + 0, vb, acc);
                av_group(w1, c * 256 + 1, vb, acc);
                av_group(w2, c * 256 + 2, vb, acc);
                av_group(w3, c * 256 + 3, vb, acc);
            }
        }
        den = lsum;
#pragma unroll
        for (int o = 32; o > 0; o >>= 1) den += __shfl_xor(den, o, 64);
    }

    outb[(size_t)i * DMODEL + h * DH + lane] = f2bf(acc / den);
}

extern "C" void kernel_launch(void* const* d_in, const int* in_sizes, int n_in,
                              void* d_out, int out_size, void* d_ws, size_t ws_size,
                              hipStream_t stream) {
    const float* x  = (const float*)d_in[0];
    const float* Wq = (const float*)d_in[1];
    const float* Wk = (const float*)d_in[2];
    const float* Wv = (const float*)d_in[3];
    const float* Wo = (const float*)d_in[4];
    float* out = (float*)d_out;

    float* ws = (float*)d_ws;
    float* q    = ws;                               // 2M floats
    float* kT   = q + (size_t)SEQ * DMODEL;         // 512K floats
    float* vv   = kT + (size_t)KV_D * SEQ;          // 512K floats
    float* ktmp = vv + (size_t)SEQ * KV_D;          // 512K floats
    unsigned short* xb  = (unsigned short*)(ktmp + (size_t)SEQ * KV_D);   // 2M bf16 (4MB)
    unsigned short* wqb = xb + (size_t)SEQ * DMODEL;                      // 1M bf16
    unsigned short* wkb = wqb + (size_t)DMODEL * DMODEL;                  // 256K bf16
    unsigned short* wvb = wkb + (size_t)KV_D * DMODEL;                    // 256K bf16
    unsigned short* wob = wvb + (size_t)KV_D * DMODEL;                    // 1M bf16
    unsigned short* attnb = xb;   // alias: x_bf16 dead after projections

    dim3 blk(256);

    // f32 -> bf16 converts
    cvt_bf16<<<(SEQ * DMODEL / 4 + 255) / 256, blk, 0, stream>>>(x, xb, SEQ * DMODEL / 4);
    cvt_bf16<<<(DMODEL * DMODEL / 4 + 255) / 256, blk, 0, stream>>>(Wq, wqb, DMODEL * DMODEL / 4);
    cvt_bf16<<<(KV_D * DMODEL / 4 + 255) / 256, blk, 0, stream>>>(Wk, wkb, KV_D * DMODEL / 4);
    cvt_bf16<<<(KV_D * DMODEL / 4 + 255) / 256, blk, 0, stream>>>(Wv, wvb, KV_D * DMODEL / 4);
    cvt_bf16<<<(DMODEL * DMODEL / 4 + 255) / 256, blk, 0, stream>>>(Wo, wob, DMODEL * DMODEL / 4);

    // QKV projections (bf16 MFMA, f32 out)
    gemm_mfma<<<dim3(DMODEL / 128, SEQ / 128), blk, 0, stream>>>(xb, wqb, q, SEQ, DMODEL, DMODEL);
    gemm_mfma<<<dim3(KV_D / 128, SEQ / 128), blk, 0, stream>>>(xb, wkb, ktmp, SEQ, KV_D, DMODEL);
    gemm_mfma<<<dim3(KV_D / 128, SEQ / 128), blk, 0, stream>>>(xb, wvb, vv, SEQ, KV_D, DMODEL);

    // RoPE
    rope_q_kernel<<<(SEQ * QH * 32 + 255) / 256, blk, 0, stream>>>(q);
    rope_k_t_kernel<<<(SEQ * KVH * 32 + 255) / 256, blk, 0, stream>>>(ktmp, kT);

    // attention (writes bf16 directly for the Wo GEMM)
    attn_wave<<<(SEQ * QH) / 4, blk, 0, stream>>>(q, kT, vv, attnb);

    // output projection
    gemm_mfma<<<dim3(DMODEL / 128, SEQ / 128), blk, 0, stream>>>(attnb, wob, out, SEQ, DMODEL, DMODEL);
}

// Round 6
// 482.651 us; speedup vs baseline: 1.7462x; 1.1728x over previous
//
#include <hip/hip_runtime.h>
#include <hip/hip_bf16.h>
#include <math.h>

#define SEQ 2048
#define DMODEL 1024
#define QH 16
#define KVH 4
#define DH 64
#define TOPK 64
#define KV_D (KVH * DH)   // 256
#define CAP 128

typedef __attribute__((ext_vector_type(8))) short short8;
typedef __attribute__((ext_vector_type(4))) float floatx4;

// ---------------- monotone float<->uint mapping for exact rank selection ----------------
__device__ __forceinline__ unsigned f2u(float f) {
    unsigned u = __float_as_uint(f);
    return (u & 0x80000000u) ? ~u : (u | 0x80000000u);
}
__device__ __forceinline__ float u2f(unsigned u) {
    unsigned v = (u & 0x80000000u) ? (u & 0x7fffffffu) : ~u;
    return __uint_as_float(v);
}
__device__ __forceinline__ unsigned short f2bf(float x) {   // RNE f32->bf16
    unsigned u = __float_as_uint(x);
    return (unsigned short)((u + 0x7fffu + ((u >> 16) & 1u)) >> 16);
}
__device__ __forceinline__ float bf2f(unsigned short h) {
    return __uint_as_float((unsigned)h << 16);
}

// ---------------- f32 -> bf16 convert (single) ----------------
__global__ __launch_bounds__(256) void cvt_bf16(const float* __restrict__ in,
                                                unsigned short* __restrict__ out, int n4) {
    int idx = blockIdx.x * 256 + threadIdx.x;
    if (idx >= n4) return;
    float4 f = ((const float4*)in)[idx];
    ushort4 o;
    o.x = f2bf(f.x); o.y = f2bf(f.y); o.z = f2bf(f.z); o.w = f2bf(f.w);
    ((ushort4*)out)[idx] = o;
}

// ---------------- f32 -> split bf16 (hi + lo) ----------------
__global__ __launch_bounds__(256) void cvt_split(const float* __restrict__ in,
                                                 unsigned short* __restrict__ hi,
                                                 unsigned short* __restrict__ lo, int n4) {
    int idx = blockIdx.x * 256 + threadIdx.x;
    if (idx >= n4) return;
    float4 f = ((const float4*)in)[idx];
    ushort4 h, l;
    h.x = f2bf(f.x); l.x = f2bf(f.x - bf2f(h.x));
    h.y = f2bf(f.y); l.y = f2bf(f.y - bf2f(h.y));
    h.z = f2bf(f.z); l.z = f2bf(f.z - bf2f(h.z));
    h.w = f2bf(f.w); l.w = f2bf(f.w - bf2f(h.w));
    ((ushort4*)hi)[idx] = h;
    ((ushort4*)lo)[idx] = l;
}

// ---------------- async 16B global->LDS ----------------
__device__ __forceinline__ void async16(const void* g, void* l) {
    __builtin_amdgcn_global_load_lds(
        (const __attribute__((address_space(1))) unsigned int*)g,
        (__attribute__((address_space(3))) unsigned int*)l, 16, 0, 0);
}

// ---------------- MFMA bf16 GEMM (single precision path): C = A * B^T ----------------
__global__ __launch_bounds__(256, 2) void gemm_mfma(const unsigned short* __restrict__ A,
                                                    const unsigned short* __restrict__ B,
                                                    float* __restrict__ C,
                                                    int M, int N, int K) {
    __shared__ unsigned short ldsA[128 * 32];
    __shared__ unsigned short ldsB[128 * 32];
    const int tid = threadIdx.x;
    const int lane = tid & 63;
    const int wid = tid >> 6;
    const int m0 = blockIdx.y * 128, n0 = blockIdx.x * 128;
    const int mq = (wid >> 1) * 64, nq = (wid & 1) * 64;

    floatx4 acc[4][4];
#pragma unroll
    for (int a = 0; a < 4; ++a)
#pragma unroll
        for (int b = 0; b < 4; ++b) acc[a][b] = (floatx4){0.f, 0.f, 0.f, 0.f};

    const int srow = tid >> 2;
    const int skb = (tid & 3) ^ ((tid >> 3) & 3);
    const unsigned short* Ag = A + (size_t)(m0 + srow) * K + skb * 8;
    const unsigned short* Bg = B + (size_t)(n0 + srow) * K + skb * 8;
    unsigned lbase = __builtin_amdgcn_readfirstlane((unsigned)(wid * 1024));
    char* la = (char*)ldsA + lbase;
    char* lb = (char*)ldsB + lbase;

    for (int k0 = 0; k0 < K; k0 += 32) {
        async16(Ag + k0, la);
        async16(Ag + (size_t)64 * K + k0, la + 4096);
        async16(Bg + k0, lb);
        async16(Bg + (size_t)64 * K + k0, lb + 4096);
        __syncthreads();

        short8 af[4], bf[4];
#pragma unroll
        for (int mt = 0; mt < 4; ++mt) {
            int row = mq + mt * 16 + (lane & 15);
            int s = ((lane >> 4) ^ ((row >> 1) & 3)) * 8;
            af[mt] = *(const short8*)&ldsA[row * 32 + s];
        }
#pragma unroll
        for (int nt = 0; nt < 4; ++nt) {
            int row = nq + nt * 16 + (lane & 15);
            int s = ((lane >> 4) ^ ((row >> 1) & 3)) * 8;
            bf[nt] = *(const short8*)&ldsB[row * 32 + s];
        }
#pragma unroll
        for (int mt = 0; mt < 4; ++mt)
#pragma unroll
            for (int nt = 0; nt < 4; ++nt)
                acc[mt][nt] = __builtin_amdgcn_mfma_f32_16x16x32_bf16(af[mt], bf[nt], acc[mt][nt], 0, 0, 0);
        __syncthreads();
    }
#pragma unroll
    for (int mt = 0; mt < 4; ++mt)
#pragma unroll
        for (int nt = 0; nt < 4; ++nt) {
            int col = n0 + nq + nt * 16 + (lane & 15);
            int rbase = m0 + mq + mt * 16 + (lane >> 4) * 4;
#pragma unroll
            for (int rr = 0; rr < 4; ++rr)
                C[(size_t)(rbase + rr) * N + col] = acc[mt][nt][rr];
        }
}

// ---------------- MFMA split-bf16 GEMM (~f32 accuracy): C = A * B^T ----------------
__global__ __launch_bounds__(256, 2) void gemm_mfma3(const unsigned short* __restrict__ Ah,
                                                     const unsigned short* __restrict__ Al,
                                                     const unsigned short* __restrict__ Bh,
                                                     const unsigned short* __restrict__ Bl,
                                                     float* __restrict__ C,
                                                     int M, int N, int K) {
    __shared__ unsigned short lAh[128 * 32];
    __shared__ unsigned short lAl[128 * 32];
    __shared__ unsigned short lBh[128 * 32];
    __shared__ unsigned short lBl[128 * 32];
    const int tid = threadIdx.x;
    const int lane = tid & 63;
    const int wid = tid >> 6;
    const int m0 = blockIdx.y * 128, n0 = blockIdx.x * 128;
    const int mq = (wid >> 1) * 64, nq = (wid & 1) * 64;

    floatx4 acc[4][4];
#pragma unroll
    for (int a = 0; a < 4; ++a)
#pragma unroll
        for (int b = 0; b < 4; ++b) acc[a][b] = (floatx4){0.f, 0.f, 0.f, 0.f};

    const int srow = tid >> 2;
    const int skb = (tid & 3) ^ ((tid >> 3) & 3);
    const size_t goff = (size_t)srow * K + skb * 8;
    const size_t goff2 = goff + (size_t)64 * K;
    const unsigned short* pAh = Ah + (size_t)m0 * K;
    const unsigned short* pAl = Al + (size_t)m0 * K;
    const unsigned short* pBh = Bh + (size_t)n0 * K;
    const unsigned short* pBl = Bl + (size_t)n0 * K;
    unsigned lbase = __builtin_amdgcn_readfirstlane((unsigned)(wid * 1024));

    for (int k0 = 0; k0 < K; k0 += 32) {
        async16(pAh + goff + k0, (char*)lAh + lbase);
        async16(pAh + goff2 + k0, (char*)lAh + lbase + 4096);
        async16(pAl + goff + k0, (char*)lAl + lbase);
        async16(pAl + goff2 + k0, (char*)lAl + lbase + 4096);
        async16(pBh + goff + k0, (char*)lBh + lbase);
        async16(pBh + goff2 + k0, (char*)lBh + lbase + 4096);
        async16(pBl + goff + k0, (char*)lBl + lbase);
        async16(pBl + goff2 + k0, (char*)lBl + lbase + 4096);
        __syncthreads();

        short8 ah[4], al[4], bh[4], bl[4];
#pragma unroll
        for (int mt = 0; mt < 4; ++mt) {
            int row = mq + mt * 16 + (lane & 15);
            int s = ((lane >> 4) ^ ((row >> 1) & 3)) * 8;
            ah[mt] = *(const short8*)&lAh[row * 32 + s];
            al[mt] = *(const short8*)&lAl[row * 32 + s];
        }
#pragma unroll
        for (int nt = 0; nt < 4; ++nt) {
            int row = nq + nt * 16 + (lane & 15);
            int s = ((lane >> 4) ^ ((row >> 1) & 3)) * 8;
            bh[nt] = *(const short8*)&lBh[row * 32 + s];
            bl[nt] = *(const short8*)&lBl[row * 32 + s];
        }
#pragma unroll
        for (int mt = 0; mt < 4; ++mt)
#pragma unroll
            for (int nt = 0; nt < 4; ++nt) {
                floatx4 a = acc[mt][nt];
                a = __builtin_amdgcn_mfma_f32_16x16x32_bf16(al[mt], bh[nt], a, 0, 0, 0);
                a = __builtin_amdgcn_mfma_f32_16x16x32_bf16(ah[mt], bl[nt], a, 0, 0, 0);
                a = __builtin_amdgcn_mfma_f32_16x16x32_bf16(ah[mt], bh[nt], a, 0, 0, 0);
                acc[mt][nt] = a;
            }
        __syncthreads();
    }
#pragma unroll
    for (int mt = 0; mt < 4; ++mt)
#pragma unroll
        for (int nt = 0; nt < 4; ++nt) {
            int col = n0 + nq + nt * 16 + (lane & 15);
            int rbase = m0 + mq + mt * 16 + (lane >> 4) * 4;
#pragma unroll
            for (int rr = 0; rr < 4; ++rr)
                C[(size_t)(rbase + rr) * N + col] = acc[mt][nt][rr];
        }
}

// ---------------- RoPE on q (f32 in) -> split bf16 qhi/qlo [t][h*64+d] ----------------
__global__ __launch_bounds__(256) void rope_q_split(const float* __restrict__ qf,
                                                    unsigned short* __restrict__ qhi,
                                                    unsigned short* __restrict__ qlo) {
    int idx = blockIdx.x * 256 + threadIdx.x;
    if (idx >= SEQ * QH * 32) return;
    int t = idx >> 9;
    int rem = idx & 511;
    int head = rem >> 5;
    int d = rem & 31;
    float inv = powf(10000.0f, -(float)d * (1.0f / 32.0f));
    float ang = (float)t * inv;
    float s, c;
    sincosf(ang, &s, &c);
    const float* p = qf + (size_t)t * DMODEL + head * DH + d;
    float lo = p[0], hi = p[32];
    float r0 = lo * c - hi * s;
    float r1 = hi * c + lo * s;
    size_t o = (size_t)t * DMODEL + head * DH + d;
    unsigned short h0 = f2bf(r0), h1 = f2bf(r1);
    qhi[o] = h0;      qhi[o + 32] = h1;
    qlo[o] = f2bf(r0 - bf2f(h0));
    qlo[o + 32] = f2bf(r1 - bf2f(h1));
}

// ---------------- RoPE on k (f32 in [t][kvh*64+d]) -> split bf16 [kvh][t][d] ----------------
__global__ __launch_bounds__(256) void rope_k_split(const float* __restrict__ ktmp,
                                                    unsigned short* __restrict__ khi,
                                                    unsigned short* __restrict__ klo) {
    int idx = blockIdx.x * 256 + threadIdx.x;
    if (idx >= SEQ * KVH * 32) return;
    int t = idx >> 7;
    int rem = idx & 127;
    int head = rem >> 5;
    int d = rem & 31;
    float inv = powf(10000.0f, -(float)d * (1.0f / 32.0f));
    float ang = (float)t * inv;
    float s, c;
    sincosf(ang, &s, &c);
    const float* p = ktmp + (size_t)t * KV_D + head * DH + d;
    float lo = p[0], hi = p[32];
    float r0 = lo * c - hi * s;
    float r1 = hi * c + lo * s;
    size_t o = ((size_t)head * SEQ + t) * DH + d;
    unsigned short h0 = f2bf(r0), h1 = f2bf(r1);
    khi[o] = h0;      khi[o + 32] = h1;
    klo[o] = f2bf(r0 - bf2f(h0));
    klo[o + 32] = f2bf(r1 - bf2f(h1));
}

// ---------------- AV fallback helper (arbitrary kept count, exact) ----------------
__device__ __forceinline__ void av_group(float w, int jbase, const float* __restrict__ vb,
                                         float& acc) {
    unsigned long long mk = __ballot(w > 0.f);
    while (mk) {
        int l = __ffsll((unsigned long long)mk) - 1;
        mk &= mk - 1;
        float wj = __shfl(w, l, 64);
        acc += wj * vb[(size_t)(jbase + l * 4) * KV_D];
    }
}

// ---------------- attention: block = (head h, 16 q-rows); 16 waves ----------------
// Phase A: split-bf16 MFMA scores into LDS S[16][2048] (f32).
// Phase B: wave w does exact top-64 + softmax + AV for row w.
__global__ __launch_bounds__(1024) void attn_block(const unsigned short* __restrict__ qhi,
                                                   const unsigned short* __restrict__ qlo,
                                                   const unsigned short* __restrict__ khi,
                                                   const unsigned short* __restrict__ klo,
                                                   const float* __restrict__ v,
                                                   unsigned short* __restrict__ outb) {
    extern __shared__ float S[];                     // [16][2048] f32 = 128 KB
    const int lane = threadIdx.x & 63;
    const int w = threadIdx.x >> 6;                  // 0..15
    const int t = 127 - blockIdx.x;                  // longest tiles first
    const int h = blockIdx.y;
    const int kvh = h >> 2;
    const int m0 = t * 16;
    const int imax = m0 + 15;

    // ---- phase A: wave w computes S[0..15][w*128 .. w*128+127] ----
    const int jslice = w * 128;
    if (jslice <= imax) {
        const int arow = m0 + (lane & 15);
        const int koff = (lane >> 4) * 8;
        size_t aidx = (size_t)arow * DMODEL + h * DH + koff;
        short8 ah0 = *(const short8*)(qhi + aidx);
        short8 ah1 = *(const short8*)(qhi + aidx + 32);
        short8 al0 = *(const short8*)(qlo + aidx);
        short8 al1 = *(const short8*)(qlo + aidx + 32);
        for (int jt = 0; jt < 8; ++jt) {
            int jb = jslice + jt * 16;
            if (jb > imax) break;
            size_t bidx = ((size_t)kvh * SEQ + jb + (lane & 15)) * DH + koff;
            short8 bh0 = *(const short8*)(khi + bidx);
            short8 bh1 = *(const short8*)(khi + bidx + 32);
            short8 bl0 = *(const short8*)(klo + bidx);
            short8 bl1 = *(const short8*)(klo + bidx + 32);
            floatx4 acc = (floatx4){0.f, 0.f, 0.f, 0.f};
            acc = __builtin_amdgcn_mfma_f32_16x16x32_bf16(al0, bh0, acc, 0, 0, 0);
            acc = __builtin_amdgcn_mfma_f32_16x16x32_bf16(al1, bh1, acc, 0, 0, 0);
            acc = __builtin_amdgcn_mfma_f32_16x16x32_bf16(ah0, bl0, acc, 0, 0, 0);
            acc = __builtin_amdgcn_mfma_f32_16x16x32_bf16(ah1, bl1, acc, 0, 0, 0);
            acc = __builtin_amdgcn_mfma_f32_16x16x32_bf16(ah0, bh0, acc, 0, 0, 0);
            acc = __builtin_amdgcn_mfma_f32_16x16x32_bf16(ah1, bh1, acc, 0, 0, 0);
            int col = jb + (lane & 15);
            int rbase = (lane >> 4) * 4;
#pragma unroll
            for (int rr = 0; rr < 4; ++rr)
                S[(size_t)(rbase + rr) * SEQ + col] = acc[rr] * 0.125f;
        }
    }
    __syncthreads();

    // ---- phase B: wave w handles row irow = m0 + w ----
    const int irow = m0 + w;
    const int cmax = (irow >> 8) + 1;                // chunks of 256 cols
    float* Srow = S + (size_t)w * SEQ;

    uint4 uv[8];
#pragma unroll
    for (int c = 0; c < 8; ++c) {
        uv[c] = make_uint4(0u, 0u, 0u, 0u);
        if (c < cmax) {
            const int j0 = c * 256 + lane * 4;
            float4 f = *(const float4*)&Srow[j0];
            uv[c].x = (j0 + 0 <= irow) ? f2u(f.x) : 0u;
            uv[c].y = (j0 + 1 <= irow) ? f2u(f.y) : 0u;
            uv[c].z = (j0 + 2 <= irow) ? f2u(f.z) : 0u;
            uv[c].w = (j0 + 3 <= irow) ? f2u(f.w) : 0u;
        }
    }

    // row max (uint domain)
    unsigned um = 0u;
#pragma unroll
    for (int c = 0; c < 8; ++c)
        um = max(um, max(max(uv[c].x, uv[c].y), max(uv[c].z, uv[c].w)));
#pragma unroll
    for (int o = 32; o > 0; o >>= 1) um = max(um, (unsigned)__shfl_xor((int)um, o, 64));
    const float mf = u2f(um);

    // exact 64th-largest: max p with count(u >= p) >= 64
    unsigned p = 1u;
    if (irow >= TOPK) {
        p = 0u;
        for (int b = 31; b >= 0; --b) {
            unsigned cand = p | (1u << b);
            int cnt = 0;
#pragma unroll
            for (int c = 0; c < 8; ++c) {
                if (c < cmax) {
                    cnt += __popcll(__ballot(uv[c].x >= cand));
                    cnt += __popcll(__ballot(uv[c].y >= cand));
                    cnt += __popcll(__ballot(uv[c].z >= cand));
                    cnt += __popcll(__ballot(uv[c].w >= cand));
                }
            }
            if (cnt >= TOPK) p = cand;
        }
    }

    // compact kept (j, w) into this wave's (now free) S row
    float* wl = Srow;                 // [0..CAP) weights
    int* jl = (int*)(Srow + CAP);     // [0..CAP) indices
    const unsigned long long lmask = (lane == 0) ? 0ull : (~0ull >> (64 - lane));
    int base = 0;
#pragma unroll
    for (int c = 0; c < 8; ++c) {
        if (c < cmax) {
#pragma unroll
            for (int e = 0; e < 4; ++e) {
                unsigned u = (e == 0) ? uv[c].x : (e == 1) ? uv[c].y : (e == 2) ? uv[c].z : uv[c].w;
                bool keep = (u >= p);
                unsigned long long mk = __ballot(keep);
                if (keep) {
                    int pos = base + __popcll(mk & lmask);
                    if (pos < CAP) {
                        wl[pos] = __expf(u2f(u) - mf);
                        jl[pos] = c * 256 + lane * 4 + e;
                    }
                }
                base += (int)__popcll(mk);
            }
        }
    }

    const float* vb = v + kvh * DH + lane;
    float acc = 0.f, den = 0.f;
    if (base <= CAP) {
#pragma unroll 8
        for (int l = 0; l < base; ++l) {
            float wv_ = wl[l];                        // broadcast ds_read
            int j = jl[l];
            den += wv_;
            acc += wv_ * vb[(size_t)j * KV_D];
        }
    } else {
        float lsum = 0.f;
#pragma unroll
        for (int c = 0; c < 8; ++c) {
            if (c < cmax) {
                float w0 = (uv[c].x >= p) ? __expf(u2f(uv[c].x) - mf) : 0.f;
                float w1 = (uv[c].y >= p) ? __expf(u2f(uv[c].y) - mf) : 0.f;
                float w2 = (uv[c].z >= p) ? __expf(u2f(uv[c].z) - mf) : 0.f;
                float w3 = (uv[c].w >= p) ? __expf(u2f(uv[c].w) - mf) : 0.f;
                lsum += (w0 + w1) + (w2 + w3);
                av_group(w0, c * 256 + 0, vb, acc);
                av_group(w1, c * 256 + 1, vb, acc);
                av_group(w2, c * 256 + 2, vb, acc);
                av_group(w3, c * 256 + 3, vb, acc);
            }
        }
        den = lsum;
#pragma unroll
        for (int o = 32; o > 0; o >>= 1) den += __shfl_xor(den, o, 64);
    }

    outb[(size_t)irow * DMODEL + h * DH + lane] = f2bf(acc / den);
}

extern "C" void kernel_launch(void* const* d_in, const int* in_sizes, int n_in,
                              void* d_out, int out_size, void* d_ws, size_t ws_size,
                              hipStream_t stream) {
    const float* x  = (const float*)d_in[0];
    const float* Wq = (const float*)d_in[1];
    const float* Wk = (const float*)d_in[2];
    const float* Wv = (const float*)d_in[3];
    const float* Wo = (const float*)d_in[4];
    float* out = (float*)d_out;

    float* ws = (float*)d_ws;
    float* vv   = ws;                                  // 512K f32
    float* ktmp = vv + (size_t)SEQ * KV_D;             // 512K f32
    unsigned short* bfp = (unsigned short*)(ktmp + (size_t)SEQ * KV_D);
    unsigned short* xhi  = bfp;                        bfp += (size_t)SEQ * DMODEL;   // 2M
    unsigned short* xlo  = bfp;                        bfp += (size_t)SEQ * DMODEL;   // 2M
    unsigned short* wqhi = bfp;                        bfp += (size_t)DMODEL * DMODEL;
    unsigned short* wqlo = bfp;                        bfp += (size_t)DMODEL * DMODEL;
    unsigned short* wkhi = bfp;                        bfp += (size_t)KV_D * DMODEL;
    unsigned short* wklo = bfp;                        bfp += (size_t)KV_D * DMODEL;
    unsigned short* wvb  = bfp;                        bfp += (size_t)KV_D * DMODEL;
    unsigned short* wob  = bfp;                        bfp += (size_t)DMODEL * DMODEL;
    unsigned short* qhi  = bfp;                        bfp += (size_t)SEQ * DMODEL;
    unsigned short* qlo  = bfp;                        bfp += (size_t)SEQ * DMODEL;
    unsigned short* khi  = bfp;                        bfp += (size_t)KVH * SEQ * DH;
    unsigned short* klo  = bfp;                        bfp += (size_t)KVH * SEQ * DH;
    unsigned short* attnb = xhi;     // x_bf16 dead after projections
    float* qf = out;                 // use d_out as f32 q scratch (overwritten at end)

    dim3 blk(256);

    // converts
    cvt_split<<<(SEQ * DMODEL / 4 + 255) / 256, blk, 0, stream>>>(x, xhi, xlo, SEQ * DMODEL / 4);
    cvt_split<<<(DMODEL * DMODEL / 4 + 255) / 256, blk, 0, stream>>>(Wq, wqhi, wqlo, DMODEL * DMODEL / 4);
    cvt_split<<<(KV_D * DMODEL / 4 + 255) / 256, blk, 0, stream>>>(Wk, wkhi, wklo, KV_D * DMODEL / 4);
    cvt_bf16<<<(KV_D * DMODEL / 4 + 255) / 256, blk, 0, stream>>>(Wv, wvb, KV_D * DMODEL / 4);
    cvt_bf16<<<(DMODEL * DMODEL / 4 + 255) / 256, blk, 0, stream>>>(Wo, wob, DMODEL * DMODEL / 4);

    // projections: q, k split-precision; v single
    gemm_mfma3<<<dim3(DMODEL / 128, SEQ / 128), blk, 0, stream>>>(xhi, xlo, wqhi, wqlo, qf, SEQ, DMODEL, DMODEL);
    gemm_mfma3<<<dim3(KV_D / 128, SEQ / 128), blk, 0, stream>>>(xhi, xlo, wkhi, wklo, ktmp, SEQ, KV_D, DMODEL);
    gemm_mfma<<<dim3(KV_D / 128, SEQ / 128), blk, 0, stream>>>(xhi, wvb, vv, SEQ, KV_D, DMODEL);

    // RoPE -> split bf16 operands for score MFMA
    rope_q_split<<<(SEQ * QH * 32 + 255) / 256, blk, 0, stream>>>(qf, qhi, qlo);
    rope_k_split<<<(SEQ * KVH * 32 + 255) / 256, blk, 0, stream>>>(ktmp, khi, klo);

    // attention
    hipFuncSetAttribute((const void*)attn_block,
                        hipFuncAttributeMaxDynamicSharedMemorySize, 131072);
    attn_block<<<dim3(SEQ / 16, QH), dim3(1024), 131072, stream>>>(qhi, qlo, khi, klo, vv, attnb);

    // output projection
    gemm_mfma<<<dim3(DMODEL / 128, SEQ / 128), blk, 0, stream>>>(attnb, wob, out, SEQ, DMODEL, DMODEL);
}

// Round 7
// 389.298 us; speedup vs baseline: 2.1650x; 1.2398x over previous
//
#include <hip/hip_runtime.h>
#include <hip/hip_bf16.h>
#include <math.h>

#define SEQ 2048
#define DMODEL 1024
#define QH 16
#define KVH 4
#define DH 64
#define TOPK 64
#define KV_D (KVH * DH)   // 256
#define CAP 128
#define SROW 2052         // padded S row stride (floats)

typedef __attribute__((ext_vector_type(8))) short short8;
typedef __attribute__((ext_vector_type(4))) float floatx4;

// ---------------- monotone float<->uint mapping ----------------
__device__ __forceinline__ unsigned f2u(float f) {
    unsigned u = __float_as_uint(f);
    return (u & 0x80000000u) ? ~u : (u | 0x80000000u);
}
__device__ __forceinline__ float u2f(unsigned u) {
    unsigned v = (u & 0x80000000u) ? (u & 0x7fffffffu) : ~u;
    return __uint_as_float(v);
}
__device__ __forceinline__ unsigned short f2bf(float x) {   // RNE f32->bf16
    unsigned u = __float_as_uint(x);
    return (unsigned short)((u + 0x7fffu + ((u >> 16) & 1u)) >> 16);
}
__device__ __forceinline__ float bf2f(unsigned short h) {
    return __uint_as_float((unsigned)h << 16);
}
__device__ __forceinline__ void split4(float4 f, ushort4& h, ushort4& l) {
    h.x = f2bf(f.x); l.x = f2bf(f.x - bf2f(h.x));
    h.y = f2bf(f.y); l.y = f2bf(f.y - bf2f(h.y));
    h.z = f2bf(f.z); l.z = f2bf(f.z - bf2f(h.z));
    h.w = f2bf(f.w); l.w = f2bf(f.w - bf2f(h.w));
}

// ---------------- fused converts: x(split) + [Wq;Wk;Wv](split) + Wo(single) ----------------
__global__ __launch_bounds__(256) void cvt_all(const float* __restrict__ x,
                                               const float* __restrict__ Wq,
                                               const float* __restrict__ Wk,
                                               const float* __restrict__ Wv,
                                               const float* __restrict__ Wo,
                                               unsigned short* __restrict__ xhi,
                                               unsigned short* __restrict__ xlo,
                                               unsigned short* __restrict__ wbhi,
                                               unsigned short* __restrict__ wblo,
                                               unsigned short* __restrict__ wo) {
    int idx = blockIdx.x * 256 + threadIdx.x;
    if (idx >= 1179648) return;
    float4 f;
    ushort4 h, l;
    if (idx < 524288) {                       // x
        f = ((const float4*)x)[idx];
        split4(f, h, l);
        ((ushort4*)xhi)[idx] = h;
        ((ushort4*)xlo)[idx] = l;
    } else if (idx < 786432) {                // Wq -> wb rows 0..1023
        int s = idx - 524288;
        f = ((const float4*)Wq)[s];
        split4(f, h, l);
        ((ushort4*)wbhi)[s] = h;
        ((ushort4*)wblo)[s] = l;
    } else if (idx < 851968) {                // Wk -> wb rows 1024..1279
        int s = idx - 786432;
        f = ((const float4*)Wk)[s];
        split4(f, h, l);
        ((ushort4*)wbhi)[idx - 524288] = h;
        ((ushort4*)wblo)[idx - 524288] = l;
    } else if (idx < 917504) {                // Wv -> wb rows 1280..1535
        int s = idx - 851968;
        f = ((const float4*)Wv)[s];
        split4(f, h, l);
        ((ushort4*)wbhi)[idx - 524288] = h;
        ((ushort4*)wblo)[idx - 524288] = l;
    } else {                                   // Wo single bf16
        int s = idx - 917504;
        f = ((const float4*)Wo)[s];
        ushort4 o;
        o.x = f2bf(f.x); o.y = f2bf(f.y); o.z = f2bf(f.z); o.w = f2bf(f.w);
        ((ushort4*)wo)[s] = o;
    }
}

// ---------------- RoPE cos/sin LUT [t][d<32] ----------------
__global__ __launch_bounds__(256) void sincos_lut(float* __restrict__ cosT,
                                                  float* __restrict__ sinT) {
    int idx = blockIdx.x * 256 + threadIdx.x;
    if (idx >= SEQ * 32) return;
    int t = idx >> 5, d = idx & 31;
    float inv = powf(10000.0f, -(float)d * (1.0f / 32.0f));
    float s, c;
    sincosf((float)t * inv, &s, &c);
    cosT[idx] = c;
    sinT[idx] = s;
}

// ---------------- async 16B global->LDS ----------------
__device__ __forceinline__ void async16(const void* g, void* l) {
    __builtin_amdgcn_global_load_lds(
        (const __attribute__((address_space(1))) unsigned int*)g,
        (__attribute__((address_space(3))) unsigned int*)l, 16, 0, 0);
}

// ---------------- fused QKV GEMM (split bf16, ~f32) + RoPE epilogue ----------------
// C[2048, 1536] = x * [Wq;Wk;Wv]^T; cols 0-1023 q (rope->qhi/qlo), 1024-1279 k
// (rope->khi/klo transposed [kvh][t][d]), 1280-1535 v (f32 vv[t][256]).
__global__ __launch_bounds__(256, 2) void gemm_qkv(const unsigned short* __restrict__ Ah,
                                                   const unsigned short* __restrict__ Al,
                                                   const unsigned short* __restrict__ Bh,
                                                   const unsigned short* __restrict__ Bl,
                                                   const float* __restrict__ cosT,
                                                   const float* __restrict__ sinT,
                                                   unsigned short* __restrict__ qhi,
                                                   unsigned short* __restrict__ qlo,
                                                   unsigned short* __restrict__ khi,
                                                   unsigned short* __restrict__ klo,
                                                   float* __restrict__ vv) {
    const int K = DMODEL;
    __shared__ unsigned short lAh[128 * 32];
    __shared__ unsigned short lAl[128 * 32];
    __shared__ unsigned short lBh[128 * 32];
    __shared__ unsigned short lBl[128 * 32];
    const int tid = threadIdx.x;
    const int lane = tid & 63;
    const int wid = tid >> 6;
    const int m0 = blockIdx.y * 128, n0 = blockIdx.x * 128;
    const int mq = (wid >> 1) * 64, nq = (wid & 1) * 64;

    floatx4 acc[4][4];
#pragma unroll
    for (int a = 0; a < 4; ++a)
#pragma unroll
        for (int b = 0; b < 4; ++b) acc[a][b] = (floatx4){0.f, 0.f, 0.f, 0.f};

    const int srow = tid >> 2;
    const int skb = (tid & 3) ^ ((tid >> 3) & 3);
    const size_t goff = (size_t)srow * K + skb * 8;
    const size_t goff2 = goff + (size_t)64 * K;
    const unsigned short* pAh = Ah + (size_t)m0 * K;
    const unsigned short* pAl = Al + (size_t)m0 * K;
    const unsigned short* pBh = Bh + (size_t)n0 * K;
    const unsigned short* pBl = Bl + (size_t)n0 * K;
    unsigned lbase = __builtin_amdgcn_readfirstlane((unsigned)(wid * 1024));

    for (int k0 = 0; k0 < K; k0 += 32) {
        async16(pAh + goff + k0, (char*)lAh + lbase);
        async16(pAh + goff2 + k0, (char*)lAh + lbase + 4096);
        async16(pAl + goff + k0, (char*)lAl + lbase);
        async16(pAl + goff2 + k0, (char*)lAl + lbase + 4096);
        async16(pBh + goff + k0, (char*)lBh + lbase);
        async16(pBh + goff2 + k0, (char*)lBh + lbase + 4096);
        async16(pBl + goff + k0, (char*)lBl + lbase);
        async16(pBl + goff2 + k0, (char*)lBl + lbase + 4096);
        __syncthreads();

        short8 ah[4], al[4], bh[4], bl[4];
#pragma unroll
        for (int mt = 0; mt < 4; ++mt) {
            int row = mq + mt * 16 + (lane & 15);
            int s = ((lane >> 4) ^ ((row >> 1) & 3)) * 8;
            ah[mt] = *(const short8*)&lAh[row * 32 + s];
            al[mt] = *(const short8*)&lAl[row * 32 + s];
        }
#pragma unroll
        for (int nt = 0; nt < 4; ++nt) {
            int row = nq + nt * 16 + (lane & 15);
            int s = ((lane >> 4) ^ ((row >> 1) & 3)) * 8;
            bh[nt] = *(const short8*)&lBh[row * 32 + s];
            bl[nt] = *(const short8*)&lBl[row * 32 + s];
        }
#pragma unroll
        for (int mt = 0; mt < 4; ++mt)
#pragma unroll
            for (int nt = 0; nt < 4; ++nt) {
                floatx4 a = acc[mt][nt];
                a = __builtin_amdgcn_mfma_f32_16x16x32_bf16(al[mt], bh[nt], a, 0, 0, 0);
                a = __builtin_amdgcn_mfma_f32_16x16x32_bf16(ah[mt], bl[nt], a, 0, 0, 0);
                a = __builtin_amdgcn_mfma_f32_16x16x32_bf16(ah[mt], bh[nt], a, 0, 0, 0);
                acc[mt][nt] = a;
            }
        __syncthreads();
    }

    // ---- epilogue ----
    if (n0 < 1280) {
        // rope path (q or k): pair (nt, nt+2) = (d, d+32), same lane
        const bool isq = (n0 < 1024);
#pragma unroll
        for (int mt = 0; mt < 4; ++mt)
#pragma unroll
            for (int nt = 0; nt < 2; ++nt) {
                const int d32 = nt * 16 + (lane & 15);
#pragma unroll
                for (int rr = 0; rr < 4; ++rr) {
                    int row = m0 + mq + mt * 16 + (lane >> 4) * 4 + rr;
                    float lo = acc[mt][nt][rr], hi = acc[mt][nt + 2][rr];
                    float c = cosT[row * 32 + d32], s = sinT[row * 32 + d32];
                    float rlo = lo * c - hi * s;
                    float rhi = hi * c + lo * s;
                    unsigned short hlo = f2bf(rlo), hhi = f2bf(rhi);
                    unsigned short llo = f2bf(rlo - bf2f(hlo));
                    unsigned short lhi = f2bf(rhi - bf2f(hhi));
                    if (isq) {
                        size_t o = (size_t)row * DMODEL + n0 + nq + d32;
                        qhi[o] = hlo; qhi[o + 32] = hhi;
                        qlo[o] = llo; qlo[o + 32] = lhi;
                    } else {
                        int kvh = (n0 + nq - 1024) >> 6;
                        size_t o = ((size_t)kvh * SEQ + row) * DH + d32;
                        khi[o] = hlo; khi[o + 32] = hhi;
                        klo[o] = llo; klo[o + 32] = lhi;
                    }
                }
            }
    } else {
        // v path: plain f32 write to vv[t][256]
#pragma unroll
        for (int mt = 0; mt < 4; ++mt)
#pragma unroll
            for (int nt = 0; nt < 4; ++nt) {
                int vcol = n0 + nq + nt * 16 + (lane & 15) - 1280;
                int rbase = m0 + mq + mt * 16 + (lane >> 4) * 4;
#pragma unroll
                for (int rr = 0; rr < 4; ++rr)
                    vv[(size_t)(rbase + rr) * KV_D + vcol] = acc[mt][nt][rr];
            }
    }
}

// ---------------- plain bf16 MFMA GEMM for the output projection ----------------
__global__ __launch_bounds__(256, 2) void gemm_mfma(const unsigned short* __restrict__ A,
                                                    const unsigned short* __restrict__ B,
                                                    float* __restrict__ C,
                                                    int M, int N, int K) {
    __shared__ unsigned short ldsA[128 * 32];
    __shared__ unsigned short ldsB[128 * 32];
    const int tid = threadIdx.x;
    const int lane = tid & 63;
    const int wid = tid >> 6;
    const int m0 = blockIdx.y * 128, n0 = blockIdx.x * 128;
    const int mq = (wid >> 1) * 64, nq = (wid & 1) * 64;

    floatx4 acc[4][4];
#pragma unroll
    for (int a = 0; a < 4; ++a)
#pragma unroll
        for (int b = 0; b < 4; ++b) acc[a][b] = (floatx4){0.f, 0.f, 0.f, 0.f};

    const int srow = tid >> 2;
    const int skb = (tid & 3) ^ ((tid >> 3) & 3);
    const unsigned short* Ag = A + (size_t)(m0 + srow) * K + skb * 8;
    const unsigned short* Bg = B + (size_t)(n0 + srow) * K + skb * 8;
    unsigned lbase = __builtin_amdgcn_readfirstlane((unsigned)(wid * 1024));
    char* la = (char*)ldsA + lbase;
    char* lb = (char*)ldsB + lbase;

    for (int k0 = 0; k0 < K; k0 += 32) {
        async16(Ag + k0, la);
        async16(Ag + (size_t)64 * K + k0, la + 4096);
        async16(Bg + k0, lb);
        async16(Bg + (size_t)64 * K + k0, lb + 4096);
        __syncthreads();

        short8 af[4], bf[4];
#pragma unroll
        for (int mt = 0; mt < 4; ++mt) {
            int row = mq + mt * 16 + (lane & 15);
            int s = ((lane >> 4) ^ ((row >> 1) & 3)) * 8;
            af[mt] = *(const short8*)&ldsA[row * 32 + s];
        }
#pragma unroll
        for (int nt = 0; nt < 4; ++nt) {
            int row = nq + nt * 16 + (lane & 15);
            int s = ((lane >> 4) ^ ((row >> 1) & 3)) * 8;
            bf[nt] = *(const short8*)&ldsB[row * 32 + s];
        }
#pragma unroll
        for (int mt = 0; mt < 4; ++mt)
#pragma unroll
            for (int nt = 0; nt < 4; ++nt)
                acc[mt][nt] = __builtin_amdgcn_mfma_f32_16x16x32_bf16(af[mt], bf[nt], acc[mt][nt], 0, 0, 0);
        __syncthreads();
    }
#pragma unroll
    for (int mt = 0; mt < 4; ++mt)
#pragma unroll
        for (int nt = 0; nt < 4; ++nt) {
            int col = n0 + nq + nt * 16 + (lane & 15);
            int rbase = m0 + mq + mt * 16 + (lane >> 4) * 4;
#pragma unroll
            for (int rr = 0; rr < 4; ++rr)
                C[(size_t)(rbase + rr) * N + col] = acc[mt][nt][rr];
        }
}

// ---------------- AV fallback helper ----------------
__device__ __forceinline__ void av_group(float w, int jbase, const float* __restrict__ vb,
                                         float& acc) {
    unsigned long long mk = __ballot(w > 0.f);
    while (mk) {
        int l = __ffsll((unsigned long long)mk) - 1;
        mk &= mk - 1;
        float wj = __shfl(w, l, 64);
        acc += wj * vb[(size_t)(jbase + l * 4) * KV_D];
    }
}

// ---------------- attention: block = (head, 16 q-rows), 16 waves ----------------
__global__ __launch_bounds__(1024, 4) void attn_block(const unsigned short* __restrict__ qhi,
                                                      const unsigned short* __restrict__ qlo,
                                                      const unsigned short* __restrict__ khi,
                                                      const unsigned short* __restrict__ klo,
                                                      const float* __restrict__ v,
                                                      unsigned short* __restrict__ outb) {
    extern __shared__ float S[];                 // [16][SROW] + pairs [16][CAP] float2
    float2* pairs = (float2*)(S + 16 * SROW);
    const int lane = threadIdx.x & 63;
    const int w = threadIdx.x >> 6;              // 0..15
    const int t = 127 - blockIdx.x;              // longest tiles first
    const int h = blockIdx.y;
    const int kvh = h >> 2;
    const int m0 = t * 16;
    const int imax = m0 + 15;

    // ---- phase A: wave w computes S[0..15][w*128 .. w*128+127] ----
    const int jslice = w * 128;
    if (jslice <= imax) {
        const int arow = m0 + (lane & 15);
        const int koff = (lane >> 4) * 8;
        size_t aidx = (size_t)arow * DMODEL + h * DH + koff;
        short8 ah0 = *(const short8*)(qhi + aidx);
        short8 ah1 = *(const short8*)(qhi + aidx + 32);
        short8 al0 = *(const short8*)(qlo + aidx);
        short8 al1 = *(const short8*)(qlo + aidx + 32);
        for (int jt = 0; jt < 8; ++jt) {
            int jb = jslice + jt * 16;
            if (jb > imax) break;
            size_t bidx = ((size_t)kvh * SEQ + jb + (lane & 15)) * DH + koff;
            short8 bh0 = *(const short8*)(khi + bidx);
            short8 bh1 = *(const short8*)(khi + bidx + 32);
            short8 bl0 = *(const short8*)(klo + bidx);
            short8 bl1 = *(const short8*)(klo + bidx + 32);
            floatx4 acc = (floatx4){0.f, 0.f, 0.f, 0.f};
            acc = __builtin_amdgcn_mfma_f32_16x16x32_bf16(al0, bh0, acc, 0, 0, 0);
            acc = __builtin_amdgcn_mfma_f32_16x16x32_bf16(al1, bh1, acc, 0, 0, 0);
            acc = __builtin_amdgcn_mfma_f32_16x16x32_bf16(ah0, bl0, acc, 0, 0, 0);
            acc = __builtin_amdgcn_mfma_f32_16x16x32_bf16(ah1, bl1, acc, 0, 0, 0);
            acc = __builtin_amdgcn_mfma_f32_16x16x32_bf16(ah0, bh0, acc, 0, 0, 0);
            acc = __builtin_amdgcn_mfma_f32_16x16x32_bf16(ah1, bh1, acc, 0, 0, 0);
            int col = jb + (lane & 15);
            int rbase = (lane >> 4) * 4;
#pragma unroll
            for (int rr = 0; rr < 4; ++rr)
                S[(size_t)(rbase + rr) * SROW + col] = acc[rr] * 0.125f;
        }
    }
    __syncthreads();

    // ---- phase B: wave w handles row irow = m0 + w ----
    const int irow = m0 + w;
    const int cmax = (irow >> 8) + 1;
    float* Srow = S + (size_t)w * SROW;
    float2* pl = pairs + w * CAP;

    uint4 uv[8];
#pragma unroll
    for (int c = 0; c < 8; ++c) {
        uv[c] = make_uint4(0u, 0u, 0u, 0u);
        if (c < cmax) {
            const int j0 = c * 256 + lane * 4;
            float4 f = *(const float4*)&Srow[j0];
            uv[c].x = (j0 + 0 <= irow) ? f2u(f.x) : 0u;
            uv[c].y = (j0 + 1 <= irow) ? f2u(f.y) : 0u;
            uv[c].z = (j0 + 2 <= irow) ? f2u(f.z) : 0u;
            uv[c].w = (j0 + 3 <= irow) ? f2u(f.w) : 0u;
        }
    }

    // per-lane max, then wave max (um) and wave min-of-lane-max (Lb)
    unsigned lmax = 0u;
#pragma unroll
    for (int c = 0; c < 8; ++c)
        lmax = max(lmax, max(max(uv[c].x, uv[c].y), max(uv[c].z, uv[c].w)));
    unsigned um = lmax, Lb = lmax;
#pragma unroll
    for (int o = 32; o > 0; o >>= 1) {
        um = max(um, (unsigned)__shfl_xor((int)um, o, 64));
        Lb = min(Lb, (unsigned)__shfl_xor((int)Lb, o, 64));
    }
    const float mf = u2f(um);

    // exact 64th-largest: max p with count(u >= p) >= 64; skip common prefix of [Lb, um]
    unsigned p = 1u;
    if (irow >= TOPK) {
        unsigned diff = Lb ^ um;
        if (diff == 0u) {
            p = um;        // >=64 values equal the max
        } else {
            int hb = 31 - __builtin_clz(diff);
            p = (hb >= 31) ? 0u : ((um >> (hb + 1)) << (hb + 1));
            for (int b = hb; b >= 0; --b) {
                unsigned cand = p | (1u << b);
                int cnt = 0;
#pragma unroll
                for (int c = 0; c < 8; ++c) {
                    if (c < cmax) {
                        cnt += __popcll(__ballot(uv[c].x >= cand));
                        cnt += __popcll(__ballot(uv[c].y >= cand));
                        cnt += __popcll(__ballot(uv[c].z >= cand));
                        cnt += __popcll(__ballot(uv[c].w >= cand));
                    }
                }
                if (cnt >= TOPK) p = cand;
            }
        }
    }

    // compact kept (w, j) pairs into LDS
    const unsigned long long lmask = (lane == 0) ? 0ull : (~0ull >> (64 - lane));
    int base = 0;
#pragma unroll
    for (int c = 0; c < 8; ++c) {
        if (c < cmax) {
#pragma unroll
            for (int e = 0; e < 4; ++e) {
                unsigned u = (e == 0) ? uv[c].x : (e == 1) ? uv[c].y : (e == 2) ? uv[c].z : uv[c].w;
                bool keep = (u >= p);
                unsigned long long mk = __ballot(keep);
                if (keep) {
                    int pos = base + __popcll(mk & lmask);
                    if (pos < CAP)
                        pl[pos] = make_float2(__expf(u2f(u) - mf),
                                              __int_as_float(c * 256 + lane * 4 + e));
                }
                base += (int)__popcll(mk);
            }
        }
    }

    const float* vb = v + kvh * DH + lane;
    float acc = 0.f, den = 0.f;
    if (base <= CAP) {
        int l = 0;
        for (; l + 16 <= base; l += 16) {
            float2 pr[16];
            float vx[16];
#pragma unroll
            for (int u = 0; u < 16; ++u) pr[u] = pl[l + u];
#pragma unroll
            for (int u = 0; u < 16; ++u)
                vx[u] = vb[(size_t)__float_as_int(pr[u].y) * KV_D];
#pragma unroll
            for (int u = 0; u < 16; ++u) { den += pr[u].x; acc += pr[u].x * vx[u]; }
        }
        for (; l < base; ++l) {
            float2 pp = pl[l];
            den += pp.x;
            acc += pp.x * vb[(size_t)__float_as_int(pp.y) * KV_D];
        }
    } else {
        // fallback (massive ties): exact re-scan of S
        float lsum = 0.f;
        for (int c = 0; c < cmax; ++c) {
            const int j0 = c * 256 + lane * 4;
            float4 f = *(const float4*)&Srow[j0];
            float fe[4] = {f.x, f.y, f.z, f.w};
#pragma unroll
            for (int e = 0; e < 4; ++e) {
                unsigned u = (j0 + e <= irow) ? f2u(fe[e]) : 0u;
                float w_ = (u >= p) ? __expf(fe[e] - mf) : 0.f;
                lsum += w_;
                av_group(w_, c * 256 + e, vb, acc);
            }
        }
        den = lsum;
#pragma unroll
        for (int o = 32; o > 0; o >>= 1) den += __shfl_xor(den, o, 64);
    }

    outb[(size_t)irow * DMODEL + h * DH + lane] = f2bf(acc / den);
}

extern "C" void kernel_launch(void* const* d_in, const int* in_sizes, int n_in,
                              void* d_out, int out_size, void* d_ws, size_t ws_size,
                              hipStream_t stream) {
    const float* x  = (const float*)d_in[0];
    const float* Wq = (const float*)d_in[1];
    const float* Wk = (const float*)d_in[2];
    const float* Wv = (const float*)d_in[3];
    const float* Wo = (const float*)d_in[4];
    float* out = (float*)d_out;

    float* ws = (float*)d_ws;
    float* vv   = ws;                               // 2048*256 f32
    float* cosT = vv + (size_t)SEQ * KV_D;          // 65536 f32
    float* sinT = cosT + SEQ * 32;                  // 65536 f32
    unsigned short* bfp = (unsigned short*)(sinT + SEQ * 32);
    unsigned short* xhi  = bfp;  bfp += (size_t)SEQ * DMODEL;      // 2M
    unsigned short* xlo  = bfp;  bfp += (size_t)SEQ * DMODEL;      // 2M
    unsigned short* wbhi = bfp;  bfp += (size_t)1536 * DMODEL;     // 1.5M
    unsigned short* wblo = bfp;  bfp += (size_t)1536 * DMODEL;     // 1.5M
    unsigned short* wob  = bfp;  bfp += (size_t)DMODEL * DMODEL;   // 1M
    unsigned short* qhi  = bfp;  bfp += (size_t)SEQ * DMODEL;      // 2M
    unsigned short* qlo  = bfp;  bfp += (size_t)SEQ * DMODEL;      // 2M
    unsigned short* khi  = bfp;  bfp += (size_t)KVH * SEQ * DH;    // 512K
    unsigned short* klo  = bfp;  bfp += (size_t)KVH * SEQ * DH;    // 512K
    unsigned short* attnb = xhi;   // xhi dead after QKV gemm

    dim3 blk(256);

    // converts + RoPE LUT
    cvt_all<<<(1179648 + 255) / 256, blk, 0, stream>>>(x, Wq, Wk, Wv, Wo,
                                                       xhi, xlo, wbhi, wblo, wob);
    sincos_lut<<<(SEQ * 32 + 255) / 256, blk, 0, stream>>>(cosT, sinT);

    // fused QKV projection + RoPE + layout
    gemm_qkv<<<dim3(1536 / 128, SEQ / 128), blk, 0, stream>>>(xhi, xlo, wbhi, wblo,
                                                              cosT, sinT,
                                                              qhi, qlo, khi, klo, vv);

    // attention
    const int attn_lds = (16 * SROW) * 4 + 16 * CAP * 8;   // 147712 B
    hipFuncSetAttribute((const void*)attn_block,
                        hipFuncAttributeMaxDynamicSharedMemorySize, attn_lds);
    attn_block<<<dim3(SEQ / 16, QH), dim3(1024), attn_lds, stream>>>(qhi, qlo, khi, klo, vv, attnb);

    // output projection
    gemm_mfma<<<dim3(DMODEL / 128, SEQ / 128), blk, 0, stream>>>(attnb, wob, out, SEQ, DMODEL, DMODEL);
}

// Round 8
// 317.397 us; speedup vs baseline: 2.6554x; 1.2265x over previous
//
#include <hip/hip_runtime.h>
#include <hip/hip_bf16.h>
#include <math.h>

#define SEQ 2048
#define DMODEL 1024
#define QH 16
#define KVH 4
#define DH 64
#define TOPK 64
#define KV_D (KVH * DH)   // 256
#define CAP 128
#define SROW 1028         // padded S row stride (floats), half-seq chunk + 4

typedef __attribute__((ext_vector_type(8))) short short8;
typedef __attribute__((ext_vector_type(4))) float floatx4;

// ---------------- monotone float<->uint mapping ----------------
__device__ __forceinline__ unsigned f2u(float f) {
    unsigned u = __float_as_uint(f);
    return (u & 0x80000000u) ? ~u : (u | 0x80000000u);
}
__device__ __forceinline__ float u2f(unsigned u) {
    unsigned v = (u & 0x80000000u) ? (u & 0x7fffffffu) : ~u;
    return __uint_as_float(v);
}
__device__ __forceinline__ unsigned short f2bf(float x) {   // RNE f32->bf16
    unsigned u = __float_as_uint(x);
    return (unsigned short)((u + 0x7fffu + ((u >> 16) & 1u)) >> 16);
}
__device__ __forceinline__ float bf2f(unsigned short h) {
    return __uint_as_float((unsigned)h << 16);
}
__device__ __forceinline__ void split4(float4 f, ushort4& h, ushort4& l) {
    h.x = f2bf(f.x); l.x = f2bf(f.x - bf2f(h.x));
    h.y = f2bf(f.y); l.y = f2bf(f.y - bf2f(h.y));
    h.z = f2bf(f.z); l.z = f2bf(f.z - bf2f(h.z));
    h.w = f2bf(f.w); l.w = f2bf(f.w - bf2f(h.w));
}

// ---------------- fused converts: x(split) + [Wq;Wk;Wv](split) + Wo(single) ----------------
__global__ __launch_bounds__(256) void cvt_all(const float* __restrict__ x,
                                               const float* __restrict__ Wq,
                                               const float* __restrict__ Wk,
                                               const float* __restrict__ Wv,
                                               const float* __restrict__ Wo,
                                               unsigned short* __restrict__ xhi,
                                               unsigned short* __restrict__ xlo,
                                               unsigned short* __restrict__ wbhi,
                                               unsigned short* __restrict__ wblo,
                                               unsigned short* __restrict__ wo) {
    int idx = blockIdx.x * 256 + threadIdx.x;
    if (idx >= 1179648) return;
    float4 f;
    ushort4 h, l;
    if (idx < 524288) {                       // x
        f = ((const float4*)x)[idx];
        split4(f, h, l);
        ((ushort4*)xhi)[idx] = h;
        ((ushort4*)xlo)[idx] = l;
    } else if (idx < 786432) {                // Wq -> wb rows 0..1023
        int s = idx - 524288;
        f = ((const float4*)Wq)[s];
        split4(f, h, l);
        ((ushort4*)wbhi)[s] = h;
        ((ushort4*)wblo)[s] = l;
    } else if (idx < 851968) {                // Wk -> wb rows 1024..1279
        int s = idx - 786432;
        f = ((const float4*)Wk)[s];
        split4(f, h, l);
        ((ushort4*)wbhi)[idx - 524288] = h;
        ((ushort4*)wblo)[idx - 524288] = l;
    } else if (idx < 917504) {                // Wv -> wb rows 1280..1535
        int s = idx - 851968;
        f = ((const float4*)Wv)[s];
        split4(f, h, l);
        ((ushort4*)wbhi)[idx - 524288] = h;
        ((ushort4*)wblo)[idx - 524288] = l;
    } else {                                   // Wo single bf16
        int s = idx - 917504;
        f = ((const float4*)Wo)[s];
        ushort4 o;
        o.x = f2bf(f.x); o.y = f2bf(f.y); o.z = f2bf(f.z); o.w = f2bf(f.w);
        ((ushort4*)wo)[s] = o;
    }
}

// ---------------- RoPE cos/sin LUT [t][d<32] ----------------
__global__ __launch_bounds__(256) void sincos_lut(float* __restrict__ cosT,
                                                  float* __restrict__ sinT) {
    int idx = blockIdx.x * 256 + threadIdx.x;
    if (idx >= SEQ * 32) return;
    int t = idx >> 5, d = idx & 31;
    float inv = powf(10000.0f, -(float)d * (1.0f / 32.0f));
    float s, c;
    sincosf((float)t * inv, &s, &c);
    cosT[idx] = c;
    sinT[idx] = s;
}

// ---------------- async 16B global->LDS ----------------
__device__ __forceinline__ void async16(const void* g, void* l) {
    __builtin_amdgcn_global_load_lds(
        (const __attribute__((address_space(1))) unsigned int*)g,
        (__attribute__((address_space(3))) unsigned int*)l, 16, 0, 0);
}

// ---------------- fused QKV GEMM (split bf16, ~f32) + RoPE epilogue ----------------
__global__ __launch_bounds__(256, 2) void gemm_qkv(const unsigned short* __restrict__ Ah,
                                                   const unsigned short* __restrict__ Al,
                                                   const unsigned short* __restrict__ Bh,
                                                   const unsigned short* __restrict__ Bl,
                                                   const float* __restrict__ cosT,
                                                   const float* __restrict__ sinT,
                                                   unsigned short* __restrict__ qhi,
                                                   unsigned short* __restrict__ qlo,
                                                   unsigned short* __restrict__ khi,
                                                   unsigned short* __restrict__ klo,
                                                   float* __restrict__ vv) {
    const int K = DMODEL;
    __shared__ unsigned short lAh[128 * 32];
    __shared__ unsigned short lAl[128 * 32];
    __shared__ unsigned short lBh[128 * 32];
    __shared__ unsigned short lBl[128 * 32];
    const int tid = threadIdx.x;
    const int lane = tid & 63;
    const int wid = tid >> 6;
    const int m0 = blockIdx.y * 128, n0 = blockIdx.x * 128;
    const int mq = (wid >> 1) * 64, nq = (wid & 1) * 64;

    floatx4 acc[4][4];
#pragma unroll
    for (int a = 0; a < 4; ++a)
#pragma unroll
        for (int b = 0; b < 4; ++b) acc[a][b] = (floatx4){0.f, 0.f, 0.f, 0.f};

    const int srow = tid >> 2;
    const int skb = (tid & 3) ^ ((tid >> 3) & 3);
    const size_t goff = (size_t)srow * K + skb * 8;
    const size_t goff2 = goff + (size_t)64 * K;
    const unsigned short* pAh = Ah + (size_t)m0 * K;
    const unsigned short* pAl = Al + (size_t)m0 * K;
    const unsigned short* pBh = Bh + (size_t)n0 * K;
    const unsigned short* pBl = Bl + (size_t)n0 * K;
    unsigned lbase = __builtin_amdgcn_readfirstlane((unsigned)(wid * 1024));

    for (int k0 = 0; k0 < K; k0 += 32) {
        async16(pAh + goff + k0, (char*)lAh + lbase);
        async16(pAh + goff2 + k0, (char*)lAh + lbase + 4096);
        async16(pAl + goff + k0, (char*)lAl + lbase);
        async16(pAl + goff2 + k0, (char*)lAl + lbase + 4096);
        async16(pBh + goff + k0, (char*)lBh + lbase);
        async16(pBh + goff2 + k0, (char*)lBh + lbase + 4096);
        async16(pBl + goff + k0, (char*)lBl + lbase);
        async16(pBl + goff2 + k0, (char*)lBl + lbase + 4096);
        __syncthreads();

        short8 ah[4], al[4], bh[4], bl[4];
#pragma unroll
        for (int mt = 0; mt < 4; ++mt) {
            int row = mq + mt * 16 + (lane & 15);
            int s = ((lane >> 4) ^ ((row >> 1) & 3)) * 8;
            ah[mt] = *(const short8*)&lAh[row * 32 + s];
            al[mt] = *(const short8*)&lAl[row * 32 + s];
        }
#pragma unroll
        for (int nt = 0; nt < 4; ++nt) {
            int row = nq + nt * 16 + (lane & 15);
            int s = ((lane >> 4) ^ ((row >> 1) & 3)) * 8;
            bh[nt] = *(const short8*)&lBh[row * 32 + s];
            bl[nt] = *(const short8*)&lBl[row * 32 + s];
        }
#pragma unroll
        for (int mt = 0; mt < 4; ++mt)
#pragma unroll
            for (int nt = 0; nt < 4; ++nt) {
                floatx4 a = acc[mt][nt];
                a = __builtin_amdgcn_mfma_f32_16x16x32_bf16(al[mt], bh[nt], a, 0, 0, 0);
                a = __builtin_amdgcn_mfma_f32_16x16x32_bf16(ah[mt], bl[nt], a, 0, 0, 0);
                a = __builtin_amdgcn_mfma_f32_16x16x32_bf16(ah[mt], bh[nt], a, 0, 0, 0);
                acc[mt][nt] = a;
            }
        __syncthreads();
    }

    // ---- epilogue ----
    if (n0 < 1280) {
        const bool isq = (n0 < 1024);
#pragma unroll
        for (int mt = 0; mt < 4; ++mt)
#pragma unroll
            for (int nt = 0; nt < 2; ++nt) {
                const int d32 = nt * 16 + (lane & 15);
#pragma unroll
                for (int rr = 0; rr < 4; ++rr) {
                    int row = m0 + mq + mt * 16 + (lane >> 4) * 4 + rr;
                    float lo = acc[mt][nt][rr], hi = acc[mt][nt + 2][rr];
                    float c = cosT[row * 32 + d32], s = sinT[row * 32 + d32];
                    float rlo = lo * c - hi * s;
                    float rhi = hi * c + lo * s;
                    unsigned short hlo = f2bf(rlo), hhi = f2bf(rhi);
                    unsigned short llo = f2bf(rlo - bf2f(hlo));
                    unsigned short lhi = f2bf(rhi - bf2f(hhi));
                    if (isq) {
                        size_t o = (size_t)row * DMODEL + n0 + nq + d32;
                        qhi[o] = hlo; qhi[o + 32] = hhi;
                        qlo[o] = llo; qlo[o + 32] = lhi;
                    } else {
                        int kvh = (n0 + nq - 1024) >> 6;
                        size_t o = ((size_t)kvh * SEQ + row) * DH + d32;
                        khi[o] = hlo; khi[o + 32] = hhi;
                        klo[o] = llo; klo[o + 32] = lhi;
                    }
                }
            }
    } else {
#pragma unroll
        for (int mt = 0; mt < 4; ++mt)
#pragma unroll
            for (int nt = 0; nt < 4; ++nt) {
                int vcol = n0 + nq + nt * 16 + (lane & 15) - 1280;
                int rbase = m0 + mq + mt * 16 + (lane >> 4) * 4;
#pragma unroll
                for (int rr = 0; rr < 4; ++rr)
                    vv[(size_t)(rbase + rr) * KV_D + vcol] = acc[mt][nt][rr];
            }
    }
}

// ---------------- plain bf16 MFMA GEMM for the output projection ----------------
__global__ __launch_bounds__(256, 2) void gemm_mfma(const unsigned short* __restrict__ A,
                                                    const unsigned short* __restrict__ B,
                                                    float* __restrict__ C,
                                                    int M, int N, int K) {
    __shared__ unsigned short ldsA[128 * 32];
    __shared__ unsigned short ldsB[128 * 32];
    const int tid = threadIdx.x;
    const int lane = tid & 63;
    const int wid = tid >> 6;
    const int m0 = blockIdx.y * 128, n0 = blockIdx.x * 128;
    const int mq = (wid >> 1) * 64, nq = (wid & 1) * 64;

    floatx4 acc[4][4];
#pragma unroll
    for (int a = 0; a < 4; ++a)
#pragma unroll
        for (int b = 0; b < 4; ++b) acc[a][b] = (floatx4){0.f, 0.f, 0.f, 0.f};

    const int srow = tid >> 2;
    const int skb = (tid & 3) ^ ((tid >> 3) & 3);
    const unsigned short* Ag = A + (size_t)(m0 + srow) * K + skb * 8;
    const unsigned short* Bg = B + (size_t)(n0 + srow) * K + skb * 8;
    unsigned lbase = __builtin_amdgcn_readfirstlane((unsigned)(wid * 1024));
    char* la = (char*)ldsA + lbase;
    char* lb = (char*)ldsB + lbase;

    for (int k0 = 0; k0 < K; k0 += 32) {
        async16(Ag + k0, la);
        async16(Ag + (size_t)64 * K + k0, la + 4096);
        async16(Bg + k0, lb);
        async16(Bg + (size_t)64 * K + k0, lb + 4096);
        __syncthreads();

        short8 af[4], bf[4];
#pragma unroll
        for (int mt = 0; mt < 4; ++mt) {
            int row = mq + mt * 16 + (lane & 15);
            int s = ((lane >> 4) ^ ((row >> 1) & 3)) * 8;
            af[mt] = *(const short8*)&ldsA[row * 32 + s];
        }
#pragma unroll
        for (int nt = 0; nt < 4; ++nt) {
            int row = nq + nt * 16 + (lane & 15);
            int s = ((lane >> 4) ^ ((row >> 1) & 3)) * 8;
            bf[nt] = *(const short8*)&ldsB[row * 32 + s];
        }
#pragma unroll
        for (int mt = 0; mt < 4; ++mt)
#pragma unroll
            for (int nt = 0; nt < 4; ++nt)
                acc[mt][nt] = __builtin_amdgcn_mfma_f32_16x16x32_bf16(af[mt], bf[nt], acc[mt][nt], 0, 0, 0);
        __syncthreads();
    }
#pragma unroll
    for (int mt = 0; mt < 4; ++mt)
#pragma unroll
        for (int nt = 0; nt < 4; ++nt) {
            int col = n0 + nq + nt * 16 + (lane & 15);
            int rbase = m0 + mq + mt * 16 + (lane >> 4) * 4;
#pragma unroll
            for (int rr = 0; rr < 4; ++rr)
                C[(size_t)(rbase + rr) * N + col] = acc[mt][nt][rr];
        }
}

// ---------------- AV fallback helper ----------------
__device__ __forceinline__ void av_group(float w, int jbase, const float* __restrict__ vb,
                                         float& acc) {
    unsigned long long mk = __ballot(w > 0.f);
    while (mk) {
        int l = __ffsll((unsigned long long)mk) - 1;
        mk &= mk - 1;
        float wj = __shfl(w, l, 64);
        acc += wj * vb[(size_t)(jbase + l * 4) * KV_D];
    }
}

// ---------------- phase-A score slice: strided j-blocks over a 1024-col chunk ----------------
__device__ __forceinline__ void score_chunk(const unsigned short* __restrict__ khi,
                                            const unsigned short* __restrict__ klo,
                                            float* __restrict__ S,
                                            const short8& ah0, const short8& ah1,
                                            const short8& al0, const short8& al1,
                                            int kvh, int w, int lane, int imax, int cbase) {
    const int koff = (lane >> 4) * 8;
#pragma unroll
    for (int n = 0; n < 4; ++n) {
        int jbi = cbase + w + n * 16;             // j-block index (16 cols each)
        int jb = jbi * 16;
        if (jb <= imax) {
            size_t bidx = ((size_t)kvh * SEQ + jb + (lane & 15)) * DH + koff;
            short8 bh0 = *(const short8*)(khi + bidx);
            short8 bh1 = *(const short8*)(khi + bidx + 32);
            short8 bl0 = *(const short8*)(klo + bidx);
            short8 bl1 = *(const short8*)(klo + bidx + 32);
            floatx4 acc = (floatx4){0.f, 0.f, 0.f, 0.f};
            acc = __builtin_amdgcn_mfma_f32_16x16x32_bf16(al0, bh0, acc, 0, 0, 0);
            acc = __builtin_amdgcn_mfma_f32_16x16x32_bf16(al1, bh1, acc, 0, 0, 0);
            acc = __builtin_amdgcn_mfma_f32_16x16x32_bf16(ah0, bl0, acc, 0, 0, 0);
            acc = __builtin_amdgcn_mfma_f32_16x16x32_bf16(ah1, bl1, acc, 0, 0, 0);
            acc = __builtin_amdgcn_mfma_f32_16x16x32_bf16(ah0, bh0, acc, 0, 0, 0);
            acc = __builtin_amdgcn_mfma_f32_16x16x32_bf16(ah1, bh1, acc, 0, 0, 0);
            int col = (jb & 1023) + (lane & 15);
            int rbase = (lane >> 4) * 4;
#pragma unroll
            for (int rr = 0; rr < 4; ++rr)
                S[(size_t)(rbase + rr) * SROW + col] = acc[rr] * 0.125f;
        }
    }
}

// ---------------- attention: block = (head, 16 q-rows), 16 waves, 2 blocks/CU ----------------
__global__ __launch_bounds__(1024, 8) void attn_block(const unsigned short* __restrict__ qhi,
                                                      const unsigned short* __restrict__ qlo,
                                                      const unsigned short* __restrict__ khi,
                                                      const unsigned short* __restrict__ klo,
                                                      const float* __restrict__ v,
                                                      unsigned short* __restrict__ outb) {
    extern __shared__ float S[];                 // [16][SROW] f32 = 65792 B; pairs aliased later
    const int lane = threadIdx.x & 63;
    const int w = threadIdx.x >> 6;              // 0..15
    const int t = 127 - blockIdx.x;              // longest tiles first
    const int h = blockIdx.y;
    const int kvh = h >> 2;
    const int m0 = t * 16;
    const int imax = m0 + 15;

    // A-fragments (q rows m0..m0+15), shared by both chunks
    const int arow = m0 + (lane & 15);
    const int koff = (lane >> 4) * 8;
    size_t aidx = (size_t)arow * DMODEL + h * DH + koff;
    short8 ah0 = *(const short8*)(qhi + aidx);
    short8 ah1 = *(const short8*)(qhi + aidx + 32);
    short8 al0 = *(const short8*)(qlo + aidx);
    short8 al1 = *(const short8*)(qlo + aidx + 32);

    const int irow = m0 + w;
    const int cmax = (irow >> 8) + 1;            // chunks of 256 cols
    float* Srow = S + (size_t)w * SROW;
    uint4 uv[8];
#pragma unroll
    for (int c = 0; c < 8; ++c) uv[c] = make_uint4(0u, 0u, 0u, 0u);

    // ---- chunk 0: cols [0,1024) ----
    score_chunk(khi, klo, S, ah0, ah1, al0, al1, kvh, w, lane, imax, 0);
    __syncthreads();
#pragma unroll
    for (int c = 0; c < 4; ++c) {
        if (c < cmax) {
            const int j0 = c * 256 + lane * 4;
            float4 f = *(const float4*)&Srow[j0];
            uv[c].x = (j0 + 0 <= irow) ? f2u(f.x) : 0u;
            uv[c].y = (j0 + 1 <= irow) ? f2u(f.y) : 0u;
            uv[c].z = (j0 + 2 <= irow) ? f2u(f.z) : 0u;
            uv[c].w = (j0 + 3 <= irow) ? f2u(f.w) : 0u;
        }
    }
    __syncthreads();

    // ---- chunk 1: cols [1024,2048) ----
    if (imax >= 1024) {
        score_chunk(khi, klo, S, ah0, ah1, al0, al1, kvh, w, lane, imax, 64);
    }
    __syncthreads();
#pragma unroll
    for (int c = 4; c < 8; ++c) {
        if (c < cmax) {
            const int j0 = (c - 4) * 256 + lane * 4;
            float4 f = *(const float4*)&Srow[j0];
            int jg = c * 256 + lane * 4;
            uv[c].x = (jg + 0 <= irow) ? f2u(f.x) : 0u;
            uv[c].y = (jg + 1 <= irow) ? f2u(f.y) : 0u;
            uv[c].z = (jg + 2 <= irow) ? f2u(f.z) : 0u;
            uv[c].w = (jg + 3 <= irow) ? f2u(f.w) : 0u;
        }
    }
    __syncthreads();                             // all uv loaded; S free for pairs

    float2* pl = (float2*)S + w * CAP;

    // per-lane max, then wave max (um) and wave min-of-lane-max (Lb)
    unsigned lmax = 0u;
#pragma unroll
    for (int c = 0; c < 8; ++c)
        lmax = max(lmax, max(max(uv[c].x, uv[c].y), max(uv[c].z, uv[c].w)));
    unsigned um = lmax, Lb = lmax;
#pragma unroll
    for (int o = 32; o > 0; o >>= 1) {
        um = max(um, (unsigned)__shfl_xor((int)um, o, 64));
        Lb = min(Lb, (unsigned)__shfl_xor((int)Lb, o, 64));
    }
    const float mf = u2f(um);

    // exact 64th-largest: max p with count(u >= p) >= 64; skip common prefix of [Lb, um]
    unsigned p = 1u;
    if (irow >= TOPK) {
        unsigned diff = Lb ^ um;
        if (diff == 0u) {
            p = um;
        } else {
            int hb = 31 - __builtin_clz(diff);
            p = (hb >= 31) ? 0u : ((um >> (hb + 1)) << (hb + 1));
            for (int b = hb; b >= 0; --b) {
                unsigned cand = p | (1u << b);
                int cnt = 0;
#pragma unroll
                for (int c = 0; c < 8; ++c) {
                    if (c < cmax) {
                        cnt += __popcll(__ballot(uv[c].x >= cand));
                        cnt += __popcll(__ballot(uv[c].y >= cand));
                        cnt += __popcll(__ballot(uv[c].z >= cand));
                        cnt += __popcll(__ballot(uv[c].w >= cand));
                    }
                }
                if (cnt >= TOPK) p = cand;
            }
        }
    }

    // compact kept (w, j) pairs into LDS
    const unsigned long long lmask = (lane == 0) ? 0ull : (~0ull >> (64 - lane));
    int base = 0;
#pragma unroll
    for (int c = 0; c < 8; ++c) {
        if (c < cmax) {
#pragma unroll
            for (int e = 0; e < 4; ++e) {
                unsigned u = (e == 0) ? uv[c].x : (e == 1) ? uv[c].y : (e == 2) ? uv[c].z : uv[c].w;
                bool keep = (u >= p);
                unsigned long long mk = __ballot(keep);
                if (keep) {
                    int pos = base + __popcll(mk & lmask);
                    if (pos < CAP)
                        pl[pos] = make_float2(__expf(u2f(u) - mf),
                                              __int_as_float(c * 256 + lane * 4 + e));
                }
                base += (int)__popcll(mk);
            }
        }
    }

    const float* vb = v + kvh * DH + lane;
    float acc = 0.f, den = 0.f;
    if (base <= CAP) {
        int l = 0;
        for (; l + 16 <= base; l += 16) {
            float2 pr[16];
            float vx[16];
#pragma unroll
            for (int u = 0; u < 16; ++u) pr[u] = pl[l + u];
#pragma unroll
            for (int u = 0; u < 16; ++u)
                vx[u] = vb[(size_t)__float_as_int(pr[u].y) * KV_D];
#pragma unroll
            for (int u = 0; u < 16; ++u) { den += pr[u].x; acc += pr[u].x * vx[u]; }
        }
        for (; l < base; ++l) {
            float2 pp = pl[l];
            den += pp.x;
            acc += pp.x * vb[(size_t)__float_as_int(pp.y) * KV_D];
        }
    } else {
        // fallback (massive ties): exact path from uv registers
        float lsum = 0.f;
#pragma unroll
        for (int c = 0; c < 8; ++c) {
            if (c < cmax) {
                float w0 = (uv[c].x >= p) ? __expf(u2f(uv[c].x) - mf) : 0.f;
                float w1 = (uv[c].y >= p) ? __expf(u2f(uv[c].y) - mf) : 0.f;
                float w2 = (uv[c].z >= p) ? __expf(u2f(uv[c].z) - mf) : 0.f;
                float w3 = (uv[c].w >= p) ? __expf(u2f(uv[c].w) - mf) : 0.f;
                lsum += (w0 + w1) + (w2 + w3);
                av_group(w0, c * 256 + 0, vb, acc);
                av_group(w1, c * 256 + 1, vb, acc);
                av_group(w2, c * 256 + 2, vb, acc);
                av_group(w3, c * 256 + 3, vb, acc);
            }
        }
        den = lsum;
#pragma unroll
        for (int o = 32; o > 0; o >>= 1) den += __shfl_xor(den, o, 64);
    }

    outb[(size_t)irow * DMODEL + h * DH + lane] = f2bf(acc / den);
}

extern "C" void kernel_launch(void* const* d_in, const int* in_sizes, int n_in,
                              void* d_out, int out_size, void* d_ws, size_t ws_size,
                              hipStream_t stream) {
    const float* x  = (const float*)d_in[0];
    const float* Wq = (const float*)d_in[1];
    const float* Wk = (const float*)d_in[2];
    const float* Wv = (const float*)d_in[3];
    const float* Wo = (const float*)d_in[4];
    float* out = (float*)d_out;

    float* ws = (float*)d_ws;
    float* vv   = ws;                               // 2048*256 f32
    float* cosT = vv + (size_t)SEQ * KV_D;          // 65536 f32
    float* sinT = cosT + SEQ * 32;                  // 65536 f32
    unsigned short* bfp = (unsigned short*)(sinT + SEQ * 32);
    unsigned short* xhi  = bfp;  bfp += (size_t)SEQ * DMODEL;      // 2M
    unsigned short* xlo  = bfp;  bfp += (size_t)SEQ * DMODEL;      // 2M
    unsigned short* wbhi = bfp;  bfp += (size_t)1536 * DMODEL;     // 1.5M
    unsigned short* wblo = bfp;  bfp += (size_t)1536 * DMODEL;     // 1.5M
    unsigned short* wob  = bfp;  bfp += (size_t)DMODEL * DMODEL;   // 1M
    unsigned short* qhi  = bfp;  bfp += (size_t)SEQ * DMODEL;      // 2M
    unsigned short* qlo  = bfp;  bfp += (size_t)SEQ * DMODEL;      // 2M
    unsigned short* khi  = bfp;  bfp += (size_t)KVH * SEQ * DH;    // 512K
    unsigned short* klo  = bfp;  bfp += (size_t)KVH * SEQ * DH;    // 512K
    unsigned short* attnb = xhi;   // xhi dead after QKV gemm

    dim3 blk(256);

    // converts + RoPE LUT
    cvt_all<<<(1179648 + 255) / 256, blk, 0, stream>>>(x, Wq, Wk, Wv, Wo,
                                                       xhi, xlo, wbhi, wblo, wob);
    sincos_lut<<<(SEQ * 32 + 255) / 256, blk, 0, stream>>>(cosT, sinT);

    // fused QKV projection + RoPE + layout
    gemm_qkv<<<dim3(1536 / 128, SEQ / 128), blk, 0, stream>>>(xhi, xlo, wbhi, wblo,
                                                              cosT, sinT,
                                                              qhi, qlo, khi, klo, vv);

    // attention: 2 blocks/CU (S = 16 x 1028 floats = 65792 B)
    const int attn_lds = 16 * SROW * 4;
    hipFuncSetAttribute((const void*)attn_block,
                        hipFuncAttributeMaxDynamicSharedMemorySize, attn_lds);
    attn_block<<<dim3(SEQ / 16, QH), dim3(1024), attn_lds, stream>>>(qhi, qlo, khi, klo, vv, attnb);

    // output projection
    gemm_mfma<<<dim3(DMODEL / 128, SEQ / 128), blk, 0, stream>>>(attnb, wob, out, SEQ, DMODEL, DMODEL);
}